// Round 1
// baseline (2603.249 us; speedup 1.0000x reference)
//
#include <hip/hip_runtime.h>
#include <hip/hip_bf16.h>

#define NN 100000
#define NE 1600000
// HID=256, HEADS=4, HEAD_DIM=64

// ---------- helpers ----------
__device__ __forceinline__ float bf2f(unsigned short u) {
    union { unsigned int i; float f; } c; c.i = ((unsigned int)u) << 16; return c.f;
}
__device__ __forceinline__ unsigned short f2bf(float f) {
    union { float f; unsigned int i; } c; c.f = f;
    unsigned int lsb = (c.i >> 16) & 1u;
    c.i += 0x7FFFu + lsb;   // round-to-nearest-even
    return (unsigned short)(c.i >> 16);
}
// order-preserving float->uint key for atomicMax
__device__ __forceinline__ unsigned int fenc(float f) {
    unsigned int u = __float_as_uint(f);
    return (u & 0x80000000u) ? ~u : (u | 0x80000000u);
}
__device__ __forceinline__ float fdec(unsigned int k) {
    unsigned int u = (k & 0x80000000u) ? (k ^ 0x80000000u) : ~k;
    return __uint_as_float(u);
}

// ---------- LayerNorm: 4 rows/block, 1 wave/row, 4 elems/lane ----------
__global__ __launch_bounds__(256) void ln_k(
    const float* __restrict__ x, const float* __restrict__ g,
    const float* __restrict__ b, float* __restrict__ y, int nrows)
{
    int w = threadIdx.x >> 6, lane = threadIdx.x & 63;
    int row = blockIdx.x * 4 + w;
    if (row >= nrows) return;
    const float4 xv = *(const float4*)(x + (size_t)row * 256 + lane * 4);
    float s  = xv.x + xv.y + xv.z + xv.w;
    float sq = xv.x*xv.x + xv.y*xv.y + xv.z*xv.z + xv.w*xv.w;
    #pragma unroll
    for (int m = 1; m < 64; m <<= 1) {
        s  += __shfl_xor(s,  m);
        sq += __shfl_xor(sq, m);
    }
    float mu  = s * (1.0f / 256.0f);
    float var = sq * (1.0f / 256.0f) - mu * mu;
    float r = rsqrtf(var + 1e-5f);
    float4 gv = *(const float4*)(g + lane * 4);
    float4 bv = *(const float4*)(b + lane * 4);
    float4 o;
    o.x = (xv.x - mu) * r * gv.x + bv.x;
    o.y = (xv.y - mu) * r * gv.y + bv.y;
    o.z = (xv.z - mu) * r * gv.z + bv.z;
    o.w = (xv.w - mu) * r * gv.w + bv.w;
    *(float4*)(y + (size_t)row * 256 + lane * 4) = o;
}

// ---------- generic f32 GEMM: C[M,N] = A[M,K] @ B[K,N] + bias (+res)(relu) ----------
// 128x64 tile, 256 threads, 8x4 per thread
template<bool OUT_BF16, bool RELU, bool RES>
__global__ __launch_bounds__(256) void gemm_k(
    const float* __restrict__ A, const float* __restrict__ B,
    const float* __restrict__ bias, void* __restrict__ outv,
    const float* __restrict__ res, int M, int N, int K)
{
    __shared__ float As[16][136];
    __shared__ float Bs[16][64];
    const int t  = threadIdx.x;
    const int tx = t & 15, ty = t >> 4;
    const int bm = blockIdx.y * 128;
    const int bn = blockIdx.x * 64;

    float c[8][4];
    #pragma unroll
    for (int i = 0; i < 8; ++i)
        #pragma unroll
        for (int j = 0; j < 4; ++j) c[i][j] = 0.f;

    const int ar = t >> 1;            // 0..127
    const int ac = (t & 1) * 8;       // 0 or 8
    const int kr = t >> 4;            // 0..15
    const int bc = (t & 15) * 4;      // 0..60
    const int arow = bm + ar;

    for (int k0 = 0; k0 < K; k0 += 16) {
        float4 a0, a1;
        if (arow < M) {
            const float* ap = A + (size_t)arow * K + k0 + ac;
            a0 = *(const float4*)ap;
            a1 = *(const float4*)(ap + 4);
        } else {
            a0 = make_float4(0.f, 0.f, 0.f, 0.f); a1 = a0;
        }
        float4 bv = *(const float4*)(B + (size_t)(k0 + kr) * N + bn + bc);
        __syncthreads();
        As[ac + 0][ar] = a0.x; As[ac + 1][ar] = a0.y;
        As[ac + 2][ar] = a0.z; As[ac + 3][ar] = a0.w;
        As[ac + 4][ar] = a1.x; As[ac + 5][ar] = a1.y;
        As[ac + 6][ar] = a1.z; As[ac + 7][ar] = a1.w;
        *(float4*)&Bs[kr][bc] = bv;
        __syncthreads();
        #pragma unroll
        for (int k = 0; k < 16; ++k) {
            float4 av0 = *(const float4*)&As[k][ty * 8];
            float4 av1 = *(const float4*)&As[k][ty * 8 + 4];
            float4 bb  = *(const float4*)&Bs[k][tx * 4];
            float aa[8] = {av0.x, av0.y, av0.z, av0.w, av1.x, av1.y, av1.z, av1.w};
            float bbv[4] = {bb.x, bb.y, bb.z, bb.w};
            #pragma unroll
            for (int i = 0; i < 8; ++i)
                #pragma unroll
                for (int j = 0; j < 4; ++j)
                    c[i][j] += aa[i] * bbv[j];
        }
    }

    const int row0 = bm + ty * 8, col0 = bn + tx * 4;
    float4 bv4 = *(const float4*)(bias + col0);
    #pragma unroll
    for (int i = 0; i < 8; ++i) {
        int row = row0 + i;
        if (row >= M) break;
        float v0 = c[i][0] + bv4.x, v1 = c[i][1] + bv4.y;
        float v2 = c[i][2] + bv4.z, v3 = c[i][3] + bv4.w;
        if (RES) {
            float4 r = *(const float4*)(res + (size_t)row * N + col0);
            v0 += r.x; v1 += r.y; v2 += r.z; v3 += r.w;
        }
        if (RELU) {
            v0 = fmaxf(v0, 0.f); v1 = fmaxf(v1, 0.f);
            v2 = fmaxf(v2, 0.f); v3 = fmaxf(v3, 0.f);
        }
        if (OUT_BF16) {
            ushort4 p;
            p.x = f2bf(v0); p.y = f2bf(v1); p.z = f2bf(v2); p.w = f2bf(v3);
            *(ushort4*)((unsigned short*)outv + (size_t)row * N + col0) = p;
        } else {
            *(float4*)((float*)outv + (size_t)row * N + col0) = make_float4(v0, v1, v2, v3);
        }
    }
}

// ---------- edge logits + segment max + degree count: 1 wave / edge ----------
__global__ __launch_bounds__(256) void edge_logits_k(
    const unsigned short* __restrict__ Q, const unsigned short* __restrict__ Km,
    const int* __restrict__ src, const int* __restrict__ dst,
    float* __restrict__ logits, unsigned int* __restrict__ segmax,
    int* __restrict__ deg, int E)
{
    int wid = threadIdx.x >> 6, lane = threadIdx.x & 63;
    int e = blockIdx.x * 4 + wid;
    if (e >= E) return;
    int s = src[e], d = dst[e];
    ushort4 qv = *(const ushort4*)(Q  + (size_t)d * 256 + lane * 4);
    ushort4 kv = *(const ushort4*)(Km + (size_t)s * 256 + lane * 4);
    float p = bf2f(qv.x) * bf2f(kv.x) + bf2f(qv.y) * bf2f(kv.y)
            + bf2f(qv.z) * bf2f(kv.z) + bf2f(qv.w) * bf2f(kv.w);
    #pragma unroll
    for (int m = 1; m < 16; m <<= 1) p += __shfl_xor(p, m);
    int head = lane >> 4;
    if ((lane & 15) == 0) {
        float lg = p * 0.125f;   // HEAD_DIM^-0.5
        logits[(size_t)e * 4 + head] = lg;
        atomicMax(segmax + (size_t)d * 4 + head, fenc(lg));
    }
    if (lane == 0) atomicAdd(deg + d, 1);
}

// ---------- exp(logit - max) + segment sum ----------
__global__ void edge_exp_k(
    float* __restrict__ ev, const int* __restrict__ dst,
    const unsigned int* __restrict__ segmax, float* __restrict__ segsum, int E4)
{
    int tid = blockIdx.x * blockDim.x + threadIdx.x;
    if (tid >= E4) return;
    int e = tid >> 2, hd = tid & 3;
    int d = dst[e];
    float mx = fdec(segmax[(size_t)d * 4 + hd]);
    float x = __expf(ev[tid] - mx);
    ev[tid] = x;
    atomicAdd(segsum + (size_t)d * 4 + hd, x);
}

// ---------- single-block exclusive scan (in place), writes total at a[n] ----------
__global__ __launch_bounds__(1024) void scan_k(int* __restrict__ a, int n)
{
    __shared__ int wsum[16];
    __shared__ int carry;
    __shared__ int tot;
    int t = threadIdx.x, lane = t & 63, w = t >> 6;
    if (t == 0) carry = 0;
    __syncthreads();
    for (int base = 0; base < n; base += 1024) {
        int i = base + t;
        int v = (i < n) ? a[i] : 0;
        int s = v;
        #pragma unroll
        for (int d2 = 1; d2 < 64; d2 <<= 1) {
            int u = __shfl_up(s, d2);
            if (lane >= d2) s += u;
        }
        if (lane == 63) wsum[w] = s;
        __syncthreads();
        if (t == 0) {
            int run = 0;
            #pragma unroll
            for (int j = 0; j < 16; ++j) { int x = wsum[j]; wsum[j] = run; run += x; }
            tot = run;
        }
        __syncthreads();
        int excl = carry + wsum[w] + (s - v);
        if (i < n) a[i] = excl;
        __syncthreads();
        if (t == 0) carry += tot;
        __syncthreads();
    }
    if (threadIdx.x == 0) a[n] = carry;
}

// ---------- CSR scatter ----------
__global__ void scatter_k(
    const int* __restrict__ dst, const int* __restrict__ off,
    int* __restrict__ cursor, int* __restrict__ eids, int E)
{
    int e = blockIdx.x * blockDim.x + threadIdx.x;
    if (e >= E) return;
    int d = dst[e];
    int pos = off[d] + atomicAdd(cursor + d, 1);
    eids[pos] = e;
}

// ---------- aggregation: 1 block / node, thread t owns output element t ----------
__global__ __launch_bounds__(256) void agg_k(
    const int* __restrict__ eids, const int* __restrict__ off,
    const int* __restrict__ src, const float* __restrict__ ev,
    const float* __restrict__ segsum, const unsigned short* __restrict__ V,
    float* __restrict__ hnew)
{
    int n = blockIdx.x;
    int t = threadIdx.x;
    int head = t >> 6;
    int e0 = off[n], e1 = off[n + 1];
    float inv = 0.f;
    if (e1 > e0) inv = 1.0f / segsum[(size_t)n * 4 + head];
    float acc = 0.f;
    for (int i = e0; i < e1; ++i) {
        int eid = eids[i];
        int s = src[eid];
        float wgt = ev[(size_t)eid * 4 + head] * inv;
        acc += bf2f(V[(size_t)s * 256 + t]) * wgt;
    }
    hnew[(size_t)n * 256 + t] = acc;
}

// ---------- host ----------
extern "C" void kernel_launch(void* const* d_in, const int* in_sizes, int n_in,
                              void* d_out, int out_size, void* d_ws, size_t ws_size,
                              hipStream_t stream)
{
    if (n_in < 19) return;
    const float* h   = (const float*)d_in[0];
    const int*   src = (const int*)d_in[1];
    const int*   dst = (const int*)d_in[2];
    const float* Wq  = (const float*)d_in[3];
    const float* bq  = (const float*)d_in[4];
    const float* Wk  = (const float*)d_in[5];
    const float* bk  = (const float*)d_in[6];
    const float* Wv  = (const float*)d_in[7];
    const float* bv  = (const float*)d_in[8];
    const float* Wo  = (const float*)d_in[9];
    const float* bo  = (const float*)d_in[10];
    const float* W1  = (const float*)d_in[11];
    const float* b1  = (const float*)d_in[12];
    const float* W2  = (const float*)d_in[13];
    const float* b2  = (const float*)d_in[14];
    const float* g1  = (const float*)d_in[15];
    const float* be1 = (const float*)d_in[16];
    const float* g2  = (const float*)d_in[17];
    const float* be2 = (const float*)d_in[18];
    float* out = (float*)d_out;

    char* w = (char*)d_ws;
    // layout (bytes):
    float*          hnorm  = (float*)(w + 0);                      // 102,400,000 ; later aliased by h_new
    unsigned short* Qb     = (unsigned short*)(w + 102400000);     //  51,200,000
    unsigned short* Kb     = (unsigned short*)(w + 153600000);     //  51,200,000
    unsigned short* Vb     = (unsigned short*)(w + 204800000);     //  51,200,000
    float*          evalb  = (float*)(w + 256000000);              //  25,600,000
    unsigned int*   segmax = (unsigned int*)(w + 281600000);       //   1,600,000
    float*          segsum = (float*)(w + 283200000);              //   1,600,000
    int*            degoff = (int*)(w + 284800000);                //     400,384 (N+1 ints)
    int*            cursor = (int*)(w + 285200384);                //     400,384
    int*            eids   = (int*)(w + 285600768);                //   6,400,000 -> ends 292,000,768
    // aliases (temporally disjoint):
    float*          hnew   = hnorm;                                // after QKV gemms done
    float*          h2n    = (float*)(w + 102400000);              // spans Qb+Kb (dead after logits)
    float*          ffnmid = (float*)(w + 204800000);              // 204,800,000 over Vb..beyond (dead after agg)

    // zero the atomically-accumulated buffers
    hipMemsetAsync(segmax, 0, 1600000, stream);
    hipMemsetAsync(segsum, 0, 1600000, stream);
    hipMemsetAsync(degoff, 0, 400384, stream);
    hipMemsetAsync(cursor, 0, 400384, stream);

    const int M = NN;
    dim3 blk(256);

    // 1. LN1
    ln_k<<<dim3((NN + 3) / 4), blk, 0, stream>>>(h, g1, be1, hnorm, NN);

    // 2. QKV gemms (bf16 out)
    dim3 g256(256 / 64, (M + 127) / 128);
    gemm_k<true, false, false><<<g256, blk, 0, stream>>>(hnorm, Wq, bq, Qb, nullptr, M, 256, 256);
    gemm_k<true, false, false><<<g256, blk, 0, stream>>>(hnorm, Wk, bk, Kb, nullptr, M, 256, 256);
    gemm_k<true, false, false><<<g256, blk, 0, stream>>>(hnorm, Wv, bv, Vb, nullptr, M, 256, 256);

    // 3. edge logits + segmax + degree
    edge_logits_k<<<dim3((NE + 3) / 4), blk, 0, stream>>>(Qb, Kb, src, dst, evalb, segmax, degoff, NE);

    // 4. exp + segsum
    edge_exp_k<<<dim3((NE * 4 + 255) / 256), blk, 0, stream>>>(evalb, dst, segmax, segsum, NE * 4);

    // 5. CSR build
    scan_k<<<dim3(1), dim3(1024), 0, stream>>>(degoff, NN);
    scatter_k<<<dim3((NE + 255) / 256), blk, 0, stream>>>(dst, degoff, cursor, eids, NE);

    // 6. aggregate messages -> hnew
    agg_k<<<dim3(NN), blk, 0, stream>>>(eids, degoff, src, evalb, segsum, Vb, hnew);

    // 7. h_mid = hnew @ Wo + bo + h   -> d_out
    gemm_k<false, false, true><<<g256, blk, 0, stream>>>(hnew, Wo, bo, out, h, M, 256, 256);

    // 8. LN2
    ln_k<<<dim3((NN + 3) / 4), blk, 0, stream>>>(out, g2, be2, h2n, NN);

    // 9. FFN
    dim3 g512(512 / 64, (M + 127) / 128);
    gemm_k<false, true, false><<<g512, blk, 0, stream>>>(h2n, W1, b1, ffnmid, nullptr, M, 512, 256);
    gemm_k<false, false, true><<<g256, blk, 0, stream>>>(ffnmid, W2, b2, out, out, M, 256, 512);
}

// Round 2
// 1369.210 us; speedup vs baseline: 1.9013x; 1.9013x over previous
//
#include <hip/hip_runtime.h>
#include <hip/hip_bf16.h>

#define NN 100000
#define NE 1600000
// HID=256, HEADS=4, HEAD_DIM=64

typedef __attribute__((ext_vector_type(8))) short bf16x8;
typedef __attribute__((ext_vector_type(4))) float f32x4;

// ---------- helpers ----------
__device__ __forceinline__ float bf2f(unsigned short u) {
    union { unsigned int i; float f; } c; c.i = ((unsigned int)u) << 16; return c.f;
}
__device__ __forceinline__ unsigned short f2bf(float f) {
    union { float f; unsigned int i; } c; c.f = f;
    unsigned int lsb = (c.i >> 16) & 1u;
    c.i += 0x7FFFu + lsb;   // round-to-nearest-even
    return (unsigned short)(c.i >> 16);
}
__device__ __forceinline__ unsigned int fenc(float f) {
    unsigned int u = __float_as_uint(f);
    return (u & 0x80000000u) ? ~u : (u | 0x80000000u);
}
__device__ __forceinline__ float fdec(unsigned int k) {
    unsigned int u = (k & 0x80000000u) ? (k ^ 0x80000000u) : ~k;
    return __uint_as_float(u);
}
__device__ __forceinline__ void gload_lds16(const void* g, void* l) {
    __builtin_amdgcn_global_load_lds(
        (const __attribute__((address_space(1))) void*)g,
        (__attribute__((address_space(3))) void*)l, 16, 0, 0);
}

// ---------- LayerNorm: 4 rows/block, 1 wave/row, bf16 out ----------
__global__ __launch_bounds__(256) void ln_k(
    const float* __restrict__ x, const float* __restrict__ g,
    const float* __restrict__ b, unsigned short* __restrict__ y, int nrows)
{
    int w = threadIdx.x >> 6, lane = threadIdx.x & 63;
    int row = blockIdx.x * 4 + w;
    if (row >= nrows) return;
    const float4 xv = *(const float4*)(x + (size_t)row * 256 + lane * 4);
    float s  = xv.x + xv.y + xv.z + xv.w;
    float sq = xv.x*xv.x + xv.y*xv.y + xv.z*xv.z + xv.w*xv.w;
    #pragma unroll
    for (int m = 1; m < 64; m <<= 1) {
        s  += __shfl_xor(s,  m);
        sq += __shfl_xor(sq, m);
    }
    float mu  = s * (1.0f / 256.0f);
    float var = sq * (1.0f / 256.0f) - mu * mu;
    float r = rsqrtf(var + 1e-5f);
    float4 gv = *(const float4*)(g + lane * 4);
    float4 bv = *(const float4*)(b + lane * 4);
    ushort4 o;
    o.x = f2bf((xv.x - mu) * r * gv.x + bv.x);
    o.y = f2bf((xv.y - mu) * r * gv.y + bv.y);
    o.z = f2bf((xv.z - mu) * r * gv.z + bv.z);
    o.w = f2bf((xv.w - mu) * r * gv.w + bv.w);
    *(ushort4*)(y + (size_t)row * 256 + lane * 4) = o;
}

// ---------- weight transpose + f32->bf16: Wt[n][k] = W[k][n] ----------
__global__ __launch_bounds__(256) void wconv_k(
    const float* __restrict__ W, unsigned short* __restrict__ Wt, int K, int N)
{
    __shared__ unsigned short tl[32][33];
    int bk = blockIdx.x * 32, bn = blockIdx.y * 32;
    int lx = threadIdx.x & 31, ly = threadIdx.x >> 5;   // ly 0..7
    #pragma unroll
    for (int r = 0; r < 32; r += 8)
        tl[ly + r][lx] = f2bf(W[(size_t)(bk + ly + r) * N + bn + lx]);
    __syncthreads();
    #pragma unroll
    for (int r = 0; r < 32; r += 8)
        Wt[(size_t)(bn + ly + r) * K + bk + lx] = tl[lx][ly + r];
}

// ---------- MFMA bf16 GEMM: C[M,N] = A[M,K] @ Wt[N,K]^T + bias (+res)(relu) ----------
// 128x128 tile, BK=32, 256 threads = 4 waves (2x2), each wave 64x64 = 4x4 frags 16x16
template<bool OUT_BF16, bool RELU, bool RES>
__global__ __launch_bounds__(256) void mgemm_k(
    const unsigned short* __restrict__ A, const unsigned short* __restrict__ Wt,
    const float* __restrict__ bias, void* __restrict__ outv,
    const float* __restrict__ res, int M, int N, int K)
{
    __shared__ __align__(16) unsigned short As[128 * 32];
    __shared__ __align__(16) unsigned short Bs[128 * 32];
    const int t = threadIdx.x;
    const int lane = t & 63;
    const int wid = t >> 6;
    const int wm = wid >> 1, wn = wid & 1;
    const int bm = blockIdx.y * 128, bn = blockIdx.x * 128;

    f32x4 acc[4][4] = {};

    // staging: linear LDS, 16B per lane-slot; global k-slot XOR-swizzled by row&3
    const int li0 = t,      r0 = li0 >> 2, s0 = (li0 & 3) ^ (r0 & 3);
    const int li1 = 256 + t, r1 = li1 >> 2, s1 = (li1 & 3) ^ (r1 & 3);
    const size_t arow0 = (size_t)min(bm + r0, M - 1) * K;
    const size_t arow1 = (size_t)min(bm + r1, M - 1) * K;
    const size_t brow0 = (size_t)(bn + r0) * K;
    const size_t brow1 = (size_t)(bn + r1) * K;

    const int fr = lane & 15;       // row within fragment
    const int fs = lane >> 4;       // k-slot 0..3
    const int rslot = fs ^ (fr & 3);  // swizzled LDS slot (same for all frags)

    for (int k0 = 0; k0 < K; k0 += 32) {
        gload_lds16(A  + arow0 + k0 + s0 * 8, As + li0 * 8);
        gload_lds16(A  + arow1 + k0 + s1 * 8, As + li1 * 8);
        gload_lds16(Wt + brow0 + k0 + s0 * 8, Bs + li0 * 8);
        gload_lds16(Wt + brow1 + k0 + s1 * 8, Bs + li1 * 8);
        __syncthreads();   // drains vmcnt -> staged data visible
        bf16x8 af[4], bfr[4];
        #pragma unroll
        for (int fm = 0; fm < 4; ++fm) {
            int ra = wm * 64 + fm * 16 + fr;
            af[fm] = *(const bf16x8*)&As[ra * 32 + rslot * 8];
        }
        #pragma unroll
        for (int fn = 0; fn < 4; ++fn) {
            int rb = wn * 64 + fn * 16 + fr;
            bfr[fn] = *(const bf16x8*)&Bs[rb * 32 + rslot * 8];
        }
        #pragma unroll
        for (int fm = 0; fm < 4; ++fm)
            #pragma unroll
            for (int fn = 0; fn < 4; ++fn)
                acc[fm][fn] = __builtin_amdgcn_mfma_f32_16x16x32_bf16(
                    af[fm], bfr[fn], acc[fm][fn], 0, 0, 0);
        __syncthreads();   // protect LDS before next-tile overwrite
    }

    // epilogue: C/D layout col=lane&15, row=(lane>>4)*4+i
    #pragma unroll
    for (int fn = 0; fn < 4; ++fn) {
        const int col = bn + wn * 64 + fn * 16 + (lane & 15);
        const float bv = bias[col];
        #pragma unroll
        for (int fm = 0; fm < 4; ++fm) {
            const int rowb = bm + wm * 64 + fm * 16 + (lane >> 4) * 4;
            #pragma unroll
            for (int i = 0; i < 4; ++i) {
                int row = rowb + i;
                if (row < M) {
                    float v = acc[fm][fn][i] + bv;
                    if (RES)  v += res[(size_t)row * N + col];
                    if (RELU) v = fmaxf(v, 0.f);
                    if (OUT_BF16) ((unsigned short*)outv)[(size_t)row * N + col] = f2bf(v);
                    else          ((float*)outv)[(size_t)row * N + col] = v;
                }
            }
        }
    }
}

// ---------- edge logits + segment max + degree count: 1 wave / edge ----------
__global__ __launch_bounds__(256) void edge_logits_k(
    const unsigned short* __restrict__ Q, const unsigned short* __restrict__ Km,
    const int* __restrict__ src, const int* __restrict__ dst,
    float* __restrict__ logits, unsigned int* __restrict__ segmax,
    int* __restrict__ deg, int E)
{
    int wid = threadIdx.x >> 6, lane = threadIdx.x & 63;
    int e = blockIdx.x * 4 + wid;
    if (e >= E) return;
    int s = src[e], d = dst[e];
    ushort4 qv = *(const ushort4*)(Q  + (size_t)d * 256 + lane * 4);
    ushort4 kv = *(const ushort4*)(Km + (size_t)s * 256 + lane * 4);
    float p = bf2f(qv.x) * bf2f(kv.x) + bf2f(qv.y) * bf2f(kv.y)
            + bf2f(qv.z) * bf2f(kv.z) + bf2f(qv.w) * bf2f(kv.w);
    #pragma unroll
    for (int m = 1; m < 16; m <<= 1) p += __shfl_xor(p, m);
    int head = lane >> 4;
    if ((lane & 15) == 0) {
        float lg = p * 0.125f;   // HEAD_DIM^-0.5
        logits[(size_t)e * 4 + head] = lg;
        atomicMax(segmax + (size_t)d * 4 + head, fenc(lg));
    }
    if (lane == 0) atomicAdd(deg + d, 1);
}

// ---------- exp(logit - max) + segment sum ----------
__global__ void edge_exp_k(
    float* __restrict__ ev, const int* __restrict__ dst,
    const unsigned int* __restrict__ segmax, float* __restrict__ segsum, int E4)
{
    int tid = blockIdx.x * blockDim.x + threadIdx.x;
    if (tid >= E4) return;
    int e = tid >> 2, hd = tid & 3;
    int d = dst[e];
    float mx = fdec(segmax[(size_t)d * 4 + hd]);
    float x = __expf(ev[tid] - mx);
    ev[tid] = x;
    atomicAdd(segsum + (size_t)d * 4 + hd, x);
}

// ---------- single-block exclusive scan (in place), total at a[n] ----------
__global__ __launch_bounds__(1024) void scan_k(int* __restrict__ a, int n)
{
    __shared__ int wsum[16];
    __shared__ int carry;
    __shared__ int tot;
    int t = threadIdx.x, lane = t & 63, w = t >> 6;
    if (t == 0) carry = 0;
    __syncthreads();
    for (int base = 0; base < n; base += 1024) {
        int i = base + t;
        int v = (i < n) ? a[i] : 0;
        int s = v;
        #pragma unroll
        for (int d2 = 1; d2 < 64; d2 <<= 1) {
            int u = __shfl_up(s, d2);
            if (lane >= d2) s += u;
        }
        if (lane == 63) wsum[w] = s;
        __syncthreads();
        if (t == 0) {
            int run = 0;
            #pragma unroll
            for (int j = 0; j < 16; ++j) { int x = wsum[j]; wsum[j] = run; run += x; }
            tot = run;
        }
        __syncthreads();
        int excl = carry + wsum[w] + (s - v);
        if (i < n) a[i] = excl;
        __syncthreads();
        if (t == 0) carry += tot;
        __syncthreads();
    }
    if (threadIdx.x == 0) a[n] = carry;
}

// ---------- CSR scatter: csr[pos] = {src, eid} ----------
__global__ void scatter_k(
    const int* __restrict__ dst, const int* __restrict__ srcarr,
    const int* __restrict__ off, int* __restrict__ cursor,
    int2* __restrict__ csr, int E)
{
    int e = blockIdx.x * blockDim.x + threadIdx.x;
    if (e >= E) return;
    int d = dst[e];
    int pos = off[d] + atomicAdd(cursor + d, 1);
    csr[pos] = make_int2(srcarr[e], e);
}

// ---------- aggregation: 1 wave / node, lane owns 4 elems, 2-edge unroll ----------
__global__ __launch_bounds__(256) void agg_k(
    const int2* __restrict__ csr, const int* __restrict__ off,
    const float* __restrict__ ev, const float* __restrict__ segsum,
    const unsigned short* __restrict__ V, unsigned short* __restrict__ hnew)
{
    int w = threadIdx.x >> 6, lane = threadIdx.x & 63;
    int n = blockIdx.x * 4 + w;
    if (n >= NN) return;
    int head = lane >> 4;
    int e0 = off[n], e1 = off[n + 1];
    float a0 = 0.f, a1 = 0.f, a2 = 0.f, a3 = 0.f;
    int i = e0;
    for (; i + 1 < e1; i += 2) {
        int2 c0 = csr[i], c1 = csr[i + 1];
        float w0 = ev[(size_t)c0.y * 4 + head];
        float w1 = ev[(size_t)c1.y * 4 + head];
        ushort4 v0 = *(const ushort4*)(V + (size_t)c0.x * 256 + lane * 4);
        ushort4 v1 = *(const ushort4*)(V + (size_t)c1.x * 256 + lane * 4);
        a0 += bf2f(v0.x) * w0 + bf2f(v1.x) * w1;
        a1 += bf2f(v0.y) * w0 + bf2f(v1.y) * w1;
        a2 += bf2f(v0.z) * w0 + bf2f(v1.z) * w1;
        a3 += bf2f(v0.w) * w0 + bf2f(v1.w) * w1;
    }
    if (i < e1) {
        int2 c0 = csr[i];
        float w0 = ev[(size_t)c0.y * 4 + head];
        ushort4 v0 = *(const ushort4*)(V + (size_t)c0.x * 256 + lane * 4);
        a0 += bf2f(v0.x) * w0;
        a1 += bf2f(v0.y) * w0;
        a2 += bf2f(v0.z) * w0;
        a3 += bf2f(v0.w) * w0;
    }
    float inv = (e1 > e0) ? 1.0f / segsum[(size_t)n * 4 + head] : 0.f;
    ushort4 o;
    o.x = f2bf(a0 * inv); o.y = f2bf(a1 * inv);
    o.z = f2bf(a2 * inv); o.w = f2bf(a3 * inv);
    *(ushort4*)(hnew + (size_t)n * 256 + lane * 4) = o;
}

// ---------- host ----------
extern "C" void kernel_launch(void* const* d_in, const int* in_sizes, int n_in,
                              void* d_out, int out_size, void* d_ws, size_t ws_size,
                              hipStream_t stream)
{
    if (n_in < 19) return;
    const float* h   = (const float*)d_in[0];
    const int*   src = (const int*)d_in[1];
    const int*   dst = (const int*)d_in[2];
    const float* Wq  = (const float*)d_in[3];
    const float* bq  = (const float*)d_in[4];
    const float* Wk  = (const float*)d_in[5];
    const float* bk  = (const float*)d_in[6];
    const float* Wv  = (const float*)d_in[7];
    const float* bv  = (const float*)d_in[8];
    const float* Wo  = (const float*)d_in[9];
    const float* bo  = (const float*)d_in[10];
    const float* W1  = (const float*)d_in[11];
    const float* b1  = (const float*)d_in[12];
    const float* W2  = (const float*)d_in[13];
    const float* b2  = (const float*)d_in[14];
    const float* g1  = (const float*)d_in[15];
    const float* be1 = (const float*)d_in[16];
    const float* g2  = (const float*)d_in[17];
    const float* be2 = (const float*)d_in[18];
    float* out = (float*)d_out;

    char* w = (char*)d_ws;
    // layout (bytes):
    unsigned short* hnormb = (unsigned short*)(w + 0);            //  51,200,000
    unsigned short* Qb     = (unsigned short*)(w + 51200000);     //  51,200,000
    unsigned short* Kb     = (unsigned short*)(w + 102400000);    //  51,200,000
    unsigned short* Vb     = (unsigned short*)(w + 153600000);    //  51,200,000
    float*          evalb  = (float*)(w + 204800000);             //  25,600,000
    unsigned int*   segmax = (unsigned int*)(w + 230400000);      //   1,600,000
    float*          segsum = (float*)(w + 232000000);             //   1,600,000
    int*            degoff = (int*)(w + 233600000);               //     400,384 (N+1)
    int*            cursor = (int*)(w + 234000384);               //     400,384
    int2*           csr    = (int2*)(w + 234400768);              //  12,800,000 -> 247,200,768
    unsigned short* Wqt    = (unsigned short*)(w + 247200768);    //     131,072
    unsigned short* Wkt    = (unsigned short*)(w + 247331840);    //     131,072
    unsigned short* Wvt    = (unsigned short*)(w + 247462912);    //     131,072
    unsigned short* Wot    = (unsigned short*)(w + 247593984);    //     131,072
    unsigned short* W1t    = (unsigned short*)(w + 247725056);    //     262,144
    unsigned short* W2t    = (unsigned short*)(w + 247987200);    //     262,144 -> 248,249,344
    // aliases (temporally disjoint):
    unsigned short* hnewb  = hnormb;                     // after QKV gemms done
    unsigned short* h2nb   = Qb;                         // Q dead after logits
    unsigned short* ffnmid = Kb;                         // K,V dead after agg: 102.4 MB span

    hipMemsetAsync(segmax, 0, 1600000, stream);
    hipMemsetAsync(segsum, 0, 1600000, stream);
    hipMemsetAsync(degoff, 0, 400384, stream);
    hipMemsetAsync(cursor, 0, 400384, stream);

    const int M = NN;
    dim3 blk(256);

    // weight conversion (transpose to [N][K] bf16)
    wconv_k<<<dim3(8, 8),  blk, 0, stream>>>(Wq, Wqt, 256, 256);
    wconv_k<<<dim3(8, 8),  blk, 0, stream>>>(Wk, Wkt, 256, 256);
    wconv_k<<<dim3(8, 8),  blk, 0, stream>>>(Wv, Wvt, 256, 256);
    wconv_k<<<dim3(8, 8),  blk, 0, stream>>>(Wo, Wot, 256, 256);
    wconv_k<<<dim3(8, 16), blk, 0, stream>>>(W1, W1t, 256, 512);
    wconv_k<<<dim3(16, 8), blk, 0, stream>>>(W2, W2t, 512, 256);

    // 1. LN1 -> bf16
    ln_k<<<dim3((NN + 3) / 4), blk, 0, stream>>>(h, g1, be1, hnormb, NN);

    // 2. QKV gemms (bf16 out)
    dim3 g2x((256 / 128), (M + 127) / 128);
    mgemm_k<true, false, false><<<g2x, blk, 0, stream>>>(hnormb, Wqt, bq, Qb, nullptr, M, 256, 256);
    mgemm_k<true, false, false><<<g2x, blk, 0, stream>>>(hnormb, Wkt, bk, Kb, nullptr, M, 256, 256);
    mgemm_k<true, false, false><<<g2x, blk, 0, stream>>>(hnormb, Wvt, bv, Vb, nullptr, M, 256, 256);

    // 3. edge logits + segmax + degree
    edge_logits_k<<<dim3((NE + 3) / 4), blk, 0, stream>>>(Qb, Kb, src, dst, evalb, segmax, degoff, NE);

    // 4. exp + segsum
    edge_exp_k<<<dim3((NE * 4 + 255) / 256), blk, 0, stream>>>(evalb, dst, segmax, segsum, NE * 4);

    // 5. CSR build
    scan_k<<<dim3(1), dim3(1024), 0, stream>>>(degoff, NN);
    scatter_k<<<dim3((NE + 255) / 256), blk, 0, stream>>>(dst, src, degoff, cursor, csr, NE);

    // 6. aggregate messages -> hnew (bf16)
    agg_k<<<dim3((NN + 3) / 4), blk, 0, stream>>>(csr, degoff, evalb, segsum, Vb, hnewb);

    // 7. h_mid = hnew @ Wo + bo + h -> d_out (f32)
    mgemm_k<false, false, true><<<g2x, blk, 0, stream>>>(hnewb, Wot, bo, out, h, M, 256, 256);

    // 8. LN2 -> bf16
    ln_k<<<dim3((NN + 3) / 4), blk, 0, stream>>>(out, g2, be2, h2nb, NN);

    // 9. FFN
    dim3 g4x((512 / 128), (M + 127) / 128);
    mgemm_k<true, true, false><<<g4x, blk, 0, stream>>>(h2nb, W1t, b1, ffnmid, nullptr, M, 512, 256);
    mgemm_k<false, false, true><<<g2x, blk, 0, stream>>>(ffnmid, W2t, b2, out, out, M, 256, 512);
}

// Round 3
// 1068.230 us; speedup vs baseline: 2.4370x; 1.2818x over previous
//
#include <hip/hip_runtime.h>
#include <hip/hip_bf16.h>

#define NN 100000
#define NE 1600000
// HID=256, HEADS=4, HEAD_DIM=64

typedef __attribute__((ext_vector_type(8))) short bf16x8;
typedef __attribute__((ext_vector_type(4))) float f32x4;

// ---------- helpers ----------
__device__ __forceinline__ float bf2f(unsigned short u) {
    union { unsigned int i; float f; } c; c.i = ((unsigned int)u) << 16; return c.f;
}
__device__ __forceinline__ unsigned short f2bf(float f) {
    union { float f; unsigned int i; } c; c.f = f;
    unsigned int lsb = (c.i >> 16) & 1u;
    c.i += 0x7FFFu + lsb;   // round-to-nearest-even
    return (unsigned short)(c.i >> 16);
}
__device__ __forceinline__ void gload_lds16(const void* g, void* l) {
    __builtin_amdgcn_global_load_lds(
        (const __attribute__((address_space(1))) void*)g,
        (__attribute__((address_space(3))) void*)l, 16, 0, 0);
}

// ---------- LayerNorm: 4 rows/block, 1 wave/row, bf16 out ----------
__global__ __launch_bounds__(256) void ln_k(
    const float* __restrict__ x, const float* __restrict__ g,
    const float* __restrict__ b, unsigned short* __restrict__ y, int nrows)
{
    int w = threadIdx.x >> 6, lane = threadIdx.x & 63;
    int row = blockIdx.x * 4 + w;
    if (row >= nrows) return;
    const float4 xv = *(const float4*)(x + (size_t)row * 256 + lane * 4);
    float s  = xv.x + xv.y + xv.z + xv.w;
    float sq = xv.x*xv.x + xv.y*xv.y + xv.z*xv.z + xv.w*xv.w;
    #pragma unroll
    for (int m = 1; m < 64; m <<= 1) {
        s  += __shfl_xor(s,  m);
        sq += __shfl_xor(sq, m);
    }
    float mu  = s * (1.0f / 256.0f);
    float var = sq * (1.0f / 256.0f) - mu * mu;
    float r = rsqrtf(var + 1e-5f);
    float4 gv = *(const float4*)(g + lane * 4);
    float4 bv = *(const float4*)(b + lane * 4);
    ushort4 o;
    o.x = f2bf((xv.x - mu) * r * gv.x + bv.x);
    o.y = f2bf((xv.y - mu) * r * gv.y + bv.y);
    o.z = f2bf((xv.z - mu) * r * gv.z + bv.z);
    o.w = f2bf((xv.w - mu) * r * gv.w + bv.w);
    *(ushort4*)(y + (size_t)row * 256 + lane * 4) = o;
}

// ---------- weight transpose + f32->bf16: Wt[n][k] = W[k][n] ----------
__global__ __launch_bounds__(256) void wconv_k(
    const float* __restrict__ W, unsigned short* __restrict__ Wt, int K, int N)
{
    __shared__ unsigned short tl[32][33];
    int bk = blockIdx.x * 32, bn = blockIdx.y * 32;
    int lx = threadIdx.x & 31, ly = threadIdx.x >> 5;   // ly 0..7
    #pragma unroll
    for (int r = 0; r < 32; r += 8)
        tl[ly + r][lx] = f2bf(W[(size_t)(bk + ly + r) * N + bn + lx]);
    __syncthreads();
    #pragma unroll
    for (int r = 0; r < 32; r += 8)
        Wt[(size_t)(bn + ly + r) * K + bk + lx] = tl[lx][ly + r];
}

// ---------- MFMA bf16 GEMM: C[M,N] = A[M,K] @ Wt[N,K]^T + bias (+res)(relu) ----------
// 128x128 tile, BK=32, 256 threads = 4 waves (2x2), each wave 64x64 = 4x4 frags 16x16
// out row stride = ldc elements, column offset = coloff (for interleaved KV writes)
template<bool OUT_BF16, bool RELU, bool RES>
__global__ __launch_bounds__(256) void mgemm_k(
    const unsigned short* __restrict__ A, const unsigned short* __restrict__ Wt,
    const float* __restrict__ bias, void* __restrict__ outv,
    const float* __restrict__ res, int M, int N, int K, int ldc, int coloff)
{
    __shared__ __align__(16) unsigned short As[128 * 32];
    __shared__ __align__(16) unsigned short Bs[128 * 32];
    const int t = threadIdx.x;
    const int lane = t & 63;
    const int wid = t >> 6;
    const int wm = wid >> 1, wn = wid & 1;
    const int bm = blockIdx.y * 128, bn = blockIdx.x * 128;

    f32x4 acc[4][4] = {};

    const int li0 = t,       r0 = li0 >> 2, s0 = (li0 & 3) ^ (r0 & 3);
    const int li1 = 256 + t, r1 = li1 >> 2, s1 = (li1 & 3) ^ (r1 & 3);
    const size_t arow0 = (size_t)min(bm + r0, M - 1) * K;
    const size_t arow1 = (size_t)min(bm + r1, M - 1) * K;
    const size_t brow0 = (size_t)(bn + r0) * K;
    const size_t brow1 = (size_t)(bn + r1) * K;

    const int fr = lane & 15;       // row within fragment
    const int fs = lane >> 4;       // k-slot 0..3
    const int rslot = fs ^ (fr & 3);  // swizzled LDS slot

    for (int k0 = 0; k0 < K; k0 += 32) {
        gload_lds16(A  + arow0 + k0 + s0 * 8, As + li0 * 8);
        gload_lds16(A  + arow1 + k0 + s1 * 8, As + li1 * 8);
        gload_lds16(Wt + brow0 + k0 + s0 * 8, Bs + li0 * 8);
        gload_lds16(Wt + brow1 + k0 + s1 * 8, Bs + li1 * 8);
        __syncthreads();
        bf16x8 af[4], bfr[4];
        #pragma unroll
        for (int fm = 0; fm < 4; ++fm) {
            int ra = wm * 64 + fm * 16 + fr;
            af[fm] = *(const bf16x8*)&As[ra * 32 + rslot * 8];
        }
        #pragma unroll
        for (int fn = 0; fn < 4; ++fn) {
            int rb = wn * 64 + fn * 16 + fr;
            bfr[fn] = *(const bf16x8*)&Bs[rb * 32 + rslot * 8];
        }
        #pragma unroll
        for (int fm = 0; fm < 4; ++fm)
            #pragma unroll
            for (int fn = 0; fn < 4; ++fn)
                acc[fm][fn] = __builtin_amdgcn_mfma_f32_16x16x32_bf16(
                    af[fm], bfr[fn], acc[fm][fn], 0, 0, 0);
        __syncthreads();
    }

    // epilogue: C/D layout col=lane&15, row=(lane>>4)*4+i
    #pragma unroll
    for (int fn = 0; fn < 4; ++fn) {
        const int col = bn + wn * 64 + fn * 16 + (lane & 15);
        const float bv = bias[col];
        #pragma unroll
        for (int fm = 0; fm < 4; ++fm) {
            const int rowb = bm + wm * 64 + fm * 16 + (lane >> 4) * 4;
            #pragma unroll
            for (int i = 0; i < 4; ++i) {
                int row = rowb + i;
                if (row < M) {
                    float v = acc[fm][fn][i] + bv;
                    if (RES)  v += res[(size_t)row * N + col];
                    if (RELU) v = fmaxf(v, 0.f);
                    size_t oi = (size_t)row * ldc + coloff + col;
                    if (OUT_BF16) ((unsigned short*)outv)[oi] = f2bf(v);
                    else          ((float*)outv)[oi] = v;
                }
            }
        }
    }
}

// ---------- degree count ----------
__global__ void degcnt_k(const int* __restrict__ dst, int* __restrict__ deg, int E)
{
    int e = blockIdx.x * blockDim.x + threadIdx.x;
    if (e < E) atomicAdd(deg + dst[e], 1);
}

// ---------- single-block exclusive scan (in place), total at a[n] ----------
__global__ __launch_bounds__(1024) void scan_k(int* __restrict__ a, int n)
{
    __shared__ int wsum[16];
    __shared__ int carry;
    __shared__ int tot;
    int t = threadIdx.x, lane = t & 63, w = t >> 6;
    if (t == 0) carry = 0;
    __syncthreads();
    for (int base = 0; base < n; base += 1024) {
        int i = base + t;
        int v = (i < n) ? a[i] : 0;
        int s = v;
        #pragma unroll
        for (int d2 = 1; d2 < 64; d2 <<= 1) {
            int u = __shfl_up(s, d2);
            if (lane >= d2) s += u;
        }
        if (lane == 63) wsum[w] = s;
        __syncthreads();
        if (t == 0) {
            int run = 0;
            #pragma unroll
            for (int j = 0; j < 16; ++j) { int x = wsum[j]; wsum[j] = run; run += x; }
            tot = run;
        }
        __syncthreads();
        int excl = carry + wsum[w] + (s - v);
        if (i < n) a[i] = excl;
        __syncthreads();
        if (t == 0) carry += tot;
        __syncthreads();
    }
    if (threadIdx.x == 0) a[n] = carry;
}

// ---------- CSR scatter: csr[pos] = src ----------
__global__ void scatter_k(
    const int* __restrict__ dst, const int* __restrict__ srcarr,
    const int* __restrict__ off, int* __restrict__ cursor,
    int* __restrict__ csr, int E)
{
    int e = blockIdx.x * blockDim.x + threadIdx.x;
    if (e >= E) return;
    int d = dst[e];
    int pos = off[d] + atomicAdd(cursor + d, 1);
    csr[pos] = srcarr[e];
}

// ---------- fused edge attention: 1 wave / node, online softmax ----------
// Q[n][256] bf16 ; KV[n][512] bf16 (K row | V row) ; hnew[n][256] bf16
__global__ __launch_bounds__(256) void attn_k(
    const int* __restrict__ csr, const int* __restrict__ off,
    const unsigned short* __restrict__ Q, const unsigned short* __restrict__ KV,
    unsigned short* __restrict__ hnew)
{
    int w = threadIdx.x >> 6, lane = threadIdx.x & 63;
    int n = blockIdx.x * 4 + w;
    if (n >= NN) return;
    int e0 = off[n], e1 = off[n + 1];

    // Q fragment: lane owns 4 contiguous dims of one head (head = lane>>4)
    ushort4 qv = *(const ushort4*)(Q + (size_t)n * 256 + lane * 4);
    const float q0 = bf2f(qv.x) * 0.125f, q1 = bf2f(qv.y) * 0.125f;
    const float q2 = bf2f(qv.z) * 0.125f, q3 = bf2f(qv.w) * 0.125f;

    float m = -1e30f, s = 0.f;
    float a0 = 0.f, a1 = 0.f, a2 = 0.f, a3 = 0.f;

    int i = e0;
    for (; i + 1 < e1; i += 2) {
        int n0 = csr[i], n1 = csr[i + 1];
        const unsigned short* r0 = KV + (size_t)n0 * 512;
        const unsigned short* r1 = KV + (size_t)n1 * 512;
        ushort4 k0 = *(const ushort4*)(r0 + lane * 4);
        ushort4 v0 = *(const ushort4*)(r0 + 256 + lane * 4);
        ushort4 k1 = *(const ushort4*)(r1 + lane * 4);
        ushort4 v1 = *(const ushort4*)(r1 + 256 + lane * 4);
        float l0 = q0 * bf2f(k0.x) + q1 * bf2f(k0.y) + q2 * bf2f(k0.z) + q3 * bf2f(k0.w);
        float l1 = q0 * bf2f(k1.x) + q1 * bf2f(k1.y) + q2 * bf2f(k1.z) + q3 * bf2f(k1.w);
        #pragma unroll
        for (int m2 = 1; m2 < 16; m2 <<= 1) {
            l0 += __shfl_xor(l0, m2);
            l1 += __shfl_xor(l1, m2);
        }
        float mn = fmaxf(m, fmaxf(l0, l1));
        float sc = __expf(m - mn);
        float p0 = __expf(l0 - mn);
        float p1 = __expf(l1 - mn);
        m = mn;
        s = s * sc + p0 + p1;
        a0 = a0 * sc + p0 * bf2f(v0.x) + p1 * bf2f(v1.x);
        a1 = a1 * sc + p0 * bf2f(v0.y) + p1 * bf2f(v1.y);
        a2 = a2 * sc + p0 * bf2f(v0.z) + p1 * bf2f(v1.z);
        a3 = a3 * sc + p0 * bf2f(v0.w) + p1 * bf2f(v1.w);
    }
    if (i < e1) {
        int n0 = csr[i];
        const unsigned short* r0 = KV + (size_t)n0 * 512;
        ushort4 k0 = *(const ushort4*)(r0 + lane * 4);
        ushort4 v0 = *(const ushort4*)(r0 + 256 + lane * 4);
        float l0 = q0 * bf2f(k0.x) + q1 * bf2f(k0.y) + q2 * bf2f(k0.z) + q3 * bf2f(k0.w);
        #pragma unroll
        for (int m2 = 1; m2 < 16; m2 <<= 1) l0 += __shfl_xor(l0, m2);
        float mn = fmaxf(m, l0);
        float sc = __expf(m - mn);
        float p0 = __expf(l0 - mn);
        m = mn;
        s = s * sc + p0;
        a0 = a0 * sc + p0 * bf2f(v0.x);
        a1 = a1 * sc + p0 * bf2f(v0.y);
        a2 = a2 * sc + p0 * bf2f(v0.z);
        a3 = a3 * sc + p0 * bf2f(v0.w);
    }
    float inv = (e1 > e0) ? 1.0f / s : 0.f;
    ushort4 o;
    o.x = f2bf(a0 * inv); o.y = f2bf(a1 * inv);
    o.z = f2bf(a2 * inv); o.w = f2bf(a3 * inv);
    *(ushort4*)(hnew + (size_t)n * 256 + lane * 4) = o;
}

// ---------- host ----------
extern "C" void kernel_launch(void* const* d_in, const int* in_sizes, int n_in,
                              void* d_out, int out_size, void* d_ws, size_t ws_size,
                              hipStream_t stream)
{
    if (n_in < 19) return;
    const float* h   = (const float*)d_in[0];
    const int*   src = (const int*)d_in[1];
    const int*   dst = (const int*)d_in[2];
    const float* Wq  = (const float*)d_in[3];
    const float* bq  = (const float*)d_in[4];
    const float* Wk  = (const float*)d_in[5];
    const float* bk  = (const float*)d_in[6];
    const float* Wv  = (const float*)d_in[7];
    const float* bv  = (const float*)d_in[8];
    const float* Wo  = (const float*)d_in[9];
    const float* bo  = (const float*)d_in[10];
    const float* W1  = (const float*)d_in[11];
    const float* b1  = (const float*)d_in[12];
    const float* W2  = (const float*)d_in[13];
    const float* b2  = (const float*)d_in[14];
    const float* g1  = (const float*)d_in[15];
    const float* be1 = (const float*)d_in[16];
    const float* g2  = (const float*)d_in[17];
    const float* be2 = (const float*)d_in[18];
    float* out = (float*)d_out;

    char* w = (char*)d_ws;
    // layout (bytes):
    unsigned short* hnormb = (unsigned short*)(w + 0);            //  51,200,000
    unsigned short* Qb     = (unsigned short*)(w + 51200000);     //  51,200,000
    unsigned short* KVb    = (unsigned short*)(w + 102400000);    // 102,400,000 (K|V interleaved)
    int*            degoff = (int*)(w + 204800000);               //     400,384 (N+1)
    int*            cursor = (int*)(w + 205200384);               //     400,384
    int*            csr    = (int*)(w + 205600768);               //   6,400,000 -> 212,000,768
    unsigned short* Wqt    = (unsigned short*)(w + 212000768);    //     131,072
    unsigned short* Wkt    = (unsigned short*)(w + 212131840);    //     131,072
    unsigned short* Wvt    = (unsigned short*)(w + 212262912);    //     131,072
    unsigned short* Wot    = (unsigned short*)(w + 212393984);    //     131,072
    unsigned short* W1t    = (unsigned short*)(w + 212525056);    //     262,144
    unsigned short* W2t    = (unsigned short*)(w + 212787200);    //     262,144 -> 213,049,344
    // aliases (temporally disjoint):
    unsigned short* hnewb  = hnormb;   // hnorm dead after QKV gemms
    unsigned short* h2nb   = Qb;       // Q dead after attn
    unsigned short* ffnmid = KVb;      // KV dead after attn (needs 102.4MB, fits exactly)

    hipMemsetAsync(degoff, 0, 400384, stream);
    hipMemsetAsync(cursor, 0, 400384, stream);

    const int M = NN;
    dim3 blk(256);

    // weight conversion (transpose to [N][K] bf16)
    wconv_k<<<dim3(8, 8),  blk, 0, stream>>>(Wq, Wqt, 256, 256);
    wconv_k<<<dim3(8, 8),  blk, 0, stream>>>(Wk, Wkt, 256, 256);
    wconv_k<<<dim3(8, 8),  blk, 0, stream>>>(Wv, Wvt, 256, 256);
    wconv_k<<<dim3(8, 8),  blk, 0, stream>>>(Wo, Wot, 256, 256);
    wconv_k<<<dim3(8, 16), blk, 0, stream>>>(W1, W1t, 256, 512);
    wconv_k<<<dim3(16, 8), blk, 0, stream>>>(W2, W2t, 512, 256);

    // CSR build (independent of LN/gemms)
    degcnt_k<<<dim3((NE + 255) / 256), blk, 0, stream>>>(dst, degoff, NE);
    scan_k<<<dim3(1), dim3(1024), 0, stream>>>(degoff, NN);
    scatter_k<<<dim3((NE + 255) / 256), blk, 0, stream>>>(dst, src, degoff, cursor, csr, NE);

    // 1. LN1 -> bf16
    ln_k<<<dim3((NN + 3) / 4), blk, 0, stream>>>(h, g1, be1, hnormb, NN);

    // 2. QKV gemms (bf16 out; K,V interleaved into KVb)
    dim3 g2x((256 / 128), (M + 127) / 128);
    mgemm_k<true, false, false><<<g2x, blk, 0, stream>>>(hnormb, Wqt, bq, Qb,  nullptr, M, 256, 256, 256, 0);
    mgemm_k<true, false, false><<<g2x, blk, 0, stream>>>(hnormb, Wkt, bk, KVb, nullptr, M, 256, 256, 512, 0);
    mgemm_k<true, false, false><<<g2x, blk, 0, stream>>>(hnormb, Wvt, bv, KVb, nullptr, M, 256, 256, 512, 256);

    // 3. fused edge attention -> hnew (bf16)
    attn_k<<<dim3((NN + 3) / 4), blk, 0, stream>>>(csr, degoff, Qb, KVb, hnewb);

    // 4. h_mid = hnew @ Wo + bo + h -> d_out (f32)
    mgemm_k<false, false, true><<<g2x, blk, 0, stream>>>(hnewb, Wot, bo, out, h, M, 256, 256, 256, 0);

    // 5. LN2 -> bf16
    ln_k<<<dim3((NN + 3) / 4), blk, 0, stream>>>(out, g2, be2, h2nb, NN);

    // 6. FFN
    dim3 g4x((512 / 128), (M + 127) / 128);
    mgemm_k<true, true, false><<<g4x, blk, 0, stream>>>(h2nb, W1t, b1, ffnmid, nullptr, M, 512, 256, 512, 0);
    mgemm_k<false, false, true><<<g2x, blk, 0, stream>>>(ffnmid, W2t, b2, out, out, M, 256, 512, 256, 0);
}

// Round 5
// 1021.671 us; speedup vs baseline: 2.5480x; 1.0456x over previous
//
#include <hip/hip_runtime.h>
#include <hip/hip_bf16.h>

#define NN 100000
#define NE 1600000
// HID=256, HEADS=4, HEAD_DIM=64

typedef __attribute__((ext_vector_type(8))) short bf16x8;
typedef __attribute__((ext_vector_type(4))) float f32x4;
typedef __attribute__((ext_vector_type(2))) unsigned int u32x2;

// ---------- helpers ----------
__device__ __forceinline__ float bf2f(unsigned short u) {
    union { unsigned int i; float f; } c; c.i = ((unsigned int)u) << 16; return c.f;
}
__device__ __forceinline__ unsigned short f2bf(float f) {
    union { float f; unsigned int i; } c; c.f = f;
    unsigned int lsb = (c.i >> 16) & 1u;
    c.i += 0x7FFFu + lsb;   // round-to-nearest-even
    return (unsigned short)(c.i >> 16);
}
__device__ __forceinline__ void gload_lds16(const void* g, void* l) {
    __builtin_amdgcn_global_load_lds(
        (const __attribute__((address_space(1))) void*)g,
        (__attribute__((address_space(3))) void*)l, 16, 0, 0);
}

// ---------- LayerNorm: 4 rows/block, 1 wave/row, bf16 out ----------
__global__ __launch_bounds__(256) void ln_k(
    const float* __restrict__ x, const float* __restrict__ g,
    const float* __restrict__ b, unsigned short* __restrict__ y, int nrows)
{
    int w = threadIdx.x >> 6, lane = threadIdx.x & 63;
    int row = blockIdx.x * 4 + w;
    if (row >= nrows) return;
    const float4 xv = *(const float4*)(x + (size_t)row * 256 + lane * 4);
    float s  = xv.x + xv.y + xv.z + xv.w;
    float sq = xv.x*xv.x + xv.y*xv.y + xv.z*xv.z + xv.w*xv.w;
    #pragma unroll
    for (int m = 1; m < 64; m <<= 1) {
        s  += __shfl_xor(s,  m);
        sq += __shfl_xor(sq, m);
    }
    float mu  = s * (1.0f / 256.0f);
    float var = sq * (1.0f / 256.0f) - mu * mu;
    float r = rsqrtf(var + 1e-5f);
    float4 gv = *(const float4*)(g + lane * 4);
    float4 bv = *(const float4*)(b + lane * 4);
    ushort4 o;
    o.x = f2bf((xv.x - mu) * r * gv.x + bv.x);
    o.y = f2bf((xv.y - mu) * r * gv.y + bv.y);
    o.z = f2bf((xv.z - mu) * r * gv.z + bv.z);
    o.w = f2bf((xv.w - mu) * r * gv.w + bv.w);
    *(ushort4*)(y + (size_t)row * 256 + lane * 4) = o;
}

// ---------- weight transpose + f32->bf16: Wt[n][k] = W[k][n] ----------
__global__ __launch_bounds__(256) void wconv_k(
    const float* __restrict__ W, unsigned short* __restrict__ Wt, int K, int N)
{
    __shared__ unsigned short tl[32][33];
    int bk = blockIdx.x * 32, bn = blockIdx.y * 32;
    int lx = threadIdx.x & 31, ly = threadIdx.x >> 5;   // ly 0..7
    #pragma unroll
    for (int r = 0; r < 32; r += 8)
        tl[ly + r][lx] = f2bf(W[(size_t)(bk + ly + r) * N + bn + lx]);
    __syncthreads();
    #pragma unroll
    for (int r = 0; r < 32; r += 8)
        Wt[(size_t)(bn + ly + r) * K + bk + lx] = tl[lx][ly + r];
}

// ---------- concat 3 bias vectors of 256 into one 768 ----------
__global__ void bcat_k(const float* __restrict__ a, const float* __restrict__ b,
                       const float* __restrict__ c, float* __restrict__ o)
{
    int t = threadIdx.x;
    o[t] = a[t]; o[256 + t] = b[t]; o[512 + t] = c[t];
}

// ---------- MFMA bf16 GEMM: C[M,N] = A[M,K] @ Wt[N,K]^T + bias (+res)(relu) ----------
// 128x128 tile, BK=32, 256 threads = 4 waves (2x2), each wave 64x64 = 4x4 frags 16x16
template<bool OUT_BF16, bool RELU, bool RES>
__global__ __launch_bounds__(256) void mgemm_k(
    const unsigned short* __restrict__ A, const unsigned short* __restrict__ Wt,
    const float* __restrict__ bias, void* __restrict__ outv,
    const float* __restrict__ res, int M, int N, int K, int ldc, int coloff)
{
    __shared__ __align__(16) unsigned short As[128 * 32];
    __shared__ __align__(16) unsigned short Bs[128 * 32];
    const int t = threadIdx.x;
    const int lane = t & 63;
    const int wid = t >> 6;
    const int wm = wid >> 1, wn = wid & 1;
    const int bm = blockIdx.y * 128, bn = blockIdx.x * 128;

    f32x4 acc[4][4] = {};

    const int li0 = t,       r0 = li0 >> 2, s0 = (li0 & 3) ^ (r0 & 3);
    const int li1 = 256 + t, r1 = li1 >> 2, s1 = (li1 & 3) ^ (r1 & 3);
    const size_t arow0 = (size_t)min(bm + r0, M - 1) * K;
    const size_t arow1 = (size_t)min(bm + r1, M - 1) * K;
    const size_t brow0 = (size_t)(bn + r0) * K;
    const size_t brow1 = (size_t)(bn + r1) * K;

    const int fr = lane & 15;       // row within fragment
    const int fs = lane >> 4;       // k-slot 0..3
    const int rslot = fs ^ (fr & 3);  // swizzled LDS slot

    for (int k0 = 0; k0 < K; k0 += 32) {
        gload_lds16(A  + arow0 + k0 + s0 * 8, As + li0 * 8);
        gload_lds16(A  + arow1 + k0 + s1 * 8, As + li1 * 8);
        gload_lds16(Wt + brow0 + k0 + s0 * 8, Bs + li0 * 8);
        gload_lds16(Wt + brow1 + k0 + s1 * 8, Bs + li1 * 8);
        __syncthreads();
        bf16x8 af[4], bfr[4];
        #pragma unroll
        for (int fm = 0; fm < 4; ++fm) {
            int ra = wm * 64 + fm * 16 + fr;
            af[fm] = *(const bf16x8*)&As[ra * 32 + rslot * 8];
        }
        #pragma unroll
        for (int fn = 0; fn < 4; ++fn) {
            int rb = wn * 64 + fn * 16 + fr;
            bfr[fn] = *(const bf16x8*)&Bs[rb * 32 + rslot * 8];
        }
        #pragma unroll
        for (int fm = 0; fm < 4; ++fm)
            #pragma unroll
            for (int fn = 0; fn < 4; ++fn)
                acc[fm][fn] = __builtin_amdgcn_mfma_f32_16x16x32_bf16(
                    af[fm], bfr[fn], acc[fm][fn], 0, 0, 0);
        __syncthreads();
    }

    // epilogue: C/D layout col=lane&15, row=(lane>>4)*4+i
    #pragma unroll
    for (int fn = 0; fn < 4; ++fn) {
        const int col = bn + wn * 64 + fn * 16 + (lane & 15);
        const float bv = bias[col];
        #pragma unroll
        for (int fm = 0; fm < 4; ++fm) {
            const int rowb = bm + wm * 64 + fm * 16 + (lane >> 4) * 4;
            #pragma unroll
            for (int i = 0; i < 4; ++i) {
                int row = rowb + i;
                if (row < M) {
                    float v = acc[fm][fn][i] + bv;
                    if (RES)  v += res[(size_t)row * N + col];
                    if (RELU) v = fmaxf(v, 0.f);
                    size_t oi = (size_t)row * ldc + coloff + col;
                    if (OUT_BF16) ((unsigned short*)outv)[oi] = f2bf(v);
                    else          ((float*)outv)[oi] = v;
                }
            }
        }
    }
}

// ---------- degree count ----------
__global__ void degcnt_k(const int* __restrict__ dst, int* __restrict__ deg, int E)
{
    int e = blockIdx.x * blockDim.x + threadIdx.x;
    if (e < E) atomicAdd(deg + dst[e], 1);
}

// ---------- single-block exclusive scan (in place), total at a[n] ----------
__global__ __launch_bounds__(1024) void scan_k(int* __restrict__ a, int n)
{
    __shared__ int wsum[16];
    __shared__ int carry;
    __shared__ int tot;
    int t = threadIdx.x, lane = t & 63, w = t >> 6;
    if (t == 0) carry = 0;
    __syncthreads();
    for (int base = 0; base < n; base += 1024) {
        int i = base + t;
        int v = (i < n) ? a[i] : 0;
        int s = v;
        #pragma unroll
        for (int d2 = 1; d2 < 64; d2 <<= 1) {
            int u = __shfl_up(s, d2);
            if (lane >= d2) s += u;
        }
        if (lane == 63) wsum[w] = s;
        __syncthreads();
        if (t == 0) {
            int run = 0;
            #pragma unroll
            for (int j = 0; j < 16; ++j) { int x = wsum[j]; wsum[j] = run; run += x; }
            tot = run;
        }
        __syncthreads();
        int excl = carry + wsum[w] + (s - v);
        if (i < n) a[i] = excl;
        __syncthreads();
        if (t == 0) carry += tot;
        __syncthreads();
    }
    if (threadIdx.x == 0) a[n] = carry;
}

// ---------- CSR scatter: csr[pos] = src ----------
__global__ void scatter_k(
    const int* __restrict__ dst, const int* __restrict__ srcarr,
    const int* __restrict__ off, int* __restrict__ cursor,
    int* __restrict__ csr, int E)
{
    int e = blockIdx.x * blockDim.x + threadIdx.x;
    if (e >= E) return;
    int d = dst[e];
    int pos = off[d] + atomicAdd(cursor + d, 1);
    csr[pos] = srcarr[e];
}

// ---------- fused edge attention: 1 wave / node, flat softmax (no max shift) ----------
// QKV[n][768] bf16: Q cols 0-255 | K cols 256-511 | V cols 512-767
__global__ __launch_bounds__(256) void attn_k(
    const int* __restrict__ csr, const int* __restrict__ off,
    const unsigned short* __restrict__ QKV, unsigned short* __restrict__ hnew)
{
    int w = threadIdx.x >> 6, lane = threadIdx.x & 63;
    int n = blockIdx.x * 4 + w;
    if (n >= NN) return;
    int e0 = off[n], e1 = off[n + 1];

    // Q fragment (streamed once -> non-temporal)
    u32x2 qr = __builtin_nontemporal_load((const u32x2*)(QKV + (size_t)n * 768 + lane * 4));
    const float q0 = bf2f((unsigned short)(qr.x & 0xffff)) * 0.125f;
    const float q1 = bf2f((unsigned short)(qr.x >> 16))    * 0.125f;
    const float q2 = bf2f((unsigned short)(qr.y & 0xffff)) * 0.125f;
    const float q3 = bf2f((unsigned short)(qr.y >> 16))    * 0.125f;

    float s = 0.f;
    float a0 = 0.f, a1 = 0.f, a2 = 0.f, a3 = 0.f;

    int i = e0;
    for (; i + 3 < e1; i += 4) {
        int n0 = csr[i], n1 = csr[i + 1], n2 = csr[i + 2], n3 = csr[i + 3];
        const unsigned short* r0 = QKV + (size_t)n0 * 768 + 256;
        const unsigned short* r1 = QKV + (size_t)n1 * 768 + 256;
        const unsigned short* r2 = QKV + (size_t)n2 * 768 + 256;
        const unsigned short* r3 = QKV + (size_t)n3 * 768 + 256;
        ushort4 k0 = *(const ushort4*)(r0 + lane * 4);
        ushort4 k1 = *(const ushort4*)(r1 + lane * 4);
        ushort4 k2 = *(const ushort4*)(r2 + lane * 4);
        ushort4 k3 = *(const ushort4*)(r3 + lane * 4);
        ushort4 v0 = *(const ushort4*)(r0 + 256 + lane * 4);
        ushort4 v1 = *(const ushort4*)(r1 + 256 + lane * 4);
        ushort4 v2 = *(const ushort4*)(r2 + 256 + lane * 4);
        ushort4 v3 = *(const ushort4*)(r3 + 256 + lane * 4);
        float l0 = q0 * bf2f(k0.x) + q1 * bf2f(k0.y) + q2 * bf2f(k0.z) + q3 * bf2f(k0.w);
        float l1 = q0 * bf2f(k1.x) + q1 * bf2f(k1.y) + q2 * bf2f(k1.z) + q3 * bf2f(k1.w);
        float l2 = q0 * bf2f(k2.x) + q1 * bf2f(k2.y) + q2 * bf2f(k2.z) + q3 * bf2f(k2.w);
        float l3 = q0 * bf2f(k3.x) + q1 * bf2f(k3.y) + q2 * bf2f(k3.z) + q3 * bf2f(k3.w);
        #pragma unroll
        for (int m2 = 1; m2 < 16; m2 <<= 1) {
            l0 += __shfl_xor(l0, m2);
            l1 += __shfl_xor(l1, m2);
            l2 += __shfl_xor(l2, m2);
            l3 += __shfl_xor(l3, m2);
        }
        float p0 = __expf(l0), p1 = __expf(l1);
        float p2 = __expf(l2), p3 = __expf(l3);
        s += (p0 + p1) + (p2 + p3);
        a0 += p0 * bf2f(v0.x) + p1 * bf2f(v1.x) + p2 * bf2f(v2.x) + p3 * bf2f(v3.x);
        a1 += p0 * bf2f(v0.y) + p1 * bf2f(v1.y) + p2 * bf2f(v2.y) + p3 * bf2f(v3.y);
        a2 += p0 * bf2f(v0.z) + p1 * bf2f(v1.z) + p2 * bf2f(v2.z) + p3 * bf2f(v3.z);
        a3 += p0 * bf2f(v0.w) + p1 * bf2f(v1.w) + p2 * bf2f(v2.w) + p3 * bf2f(v3.w);
    }
    for (; i < e1; ++i) {
        int n0 = csr[i];
        const unsigned short* r0 = QKV + (size_t)n0 * 768 + 256;
        ushort4 k0 = *(const ushort4*)(r0 + lane * 4);
        ushort4 v0 = *(const ushort4*)(r0 + 256 + lane * 4);
        float l0 = q0 * bf2f(k0.x) + q1 * bf2f(k0.y) + q2 * bf2f(k0.z) + q3 * bf2f(k0.w);
        #pragma unroll
        for (int m2 = 1; m2 < 16; m2 <<= 1) l0 += __shfl_xor(l0, m2);
        float p0 = __expf(l0);
        s += p0;
        a0 += p0 * bf2f(v0.x);
        a1 += p0 * bf2f(v0.y);
        a2 += p0 * bf2f(v0.z);
        a3 += p0 * bf2f(v0.w);
    }
    float inv = (e1 > e0) ? 1.0f / s : 0.f;
    u32x2 ov;
    ov.x = ((unsigned int)f2bf(a1 * inv) << 16) | f2bf(a0 * inv);
    ov.y = ((unsigned int)f2bf(a3 * inv) << 16) | f2bf(a2 * inv);
    __builtin_nontemporal_store(ov, (u32x2*)(hnew + (size_t)n * 256 + lane * 4));
}

// ---------- host ----------
extern "C" void kernel_launch(void* const* d_in, const int* in_sizes, int n_in,
                              void* d_out, int out_size, void* d_ws, size_t ws_size,
                              hipStream_t stream)
{
    if (n_in < 19) return;
    const float* h   = (const float*)d_in[0];
    const int*   src = (const int*)d_in[1];
    const int*   dst = (const int*)d_in[2];
    const float* Wq  = (const float*)d_in[3];
    const float* bq  = (const float*)d_in[4];
    const float* Wk  = (const float*)d_in[5];
    const float* bk  = (const float*)d_in[6];
    const float* Wv  = (const float*)d_in[7];
    const float* bv  = (const float*)d_in[8];
    const float* Wo  = (const float*)d_in[9];
    const float* bo  = (const float*)d_in[10];
    const float* W1  = (const float*)d_in[11];
    const float* b1  = (const float*)d_in[12];
    const float* W2  = (const float*)d_in[13];
    const float* b2  = (const float*)d_in[14];
    const float* g1  = (const float*)d_in[15];
    const float* be1 = (const float*)d_in[16];
    const float* g2  = (const float*)d_in[17];
    const float* be2 = (const float*)d_in[18];
    float* out = (float*)d_out;

    char* w = (char*)d_ws;
    // layout (bytes):
    unsigned short* hnormb = (unsigned short*)(w + 0);            //  51,200,000
    unsigned short* QKVb   = (unsigned short*)(w + 51200000);     // 153,600,000 (Q|K|V interleaved)
    int*            degoff = (int*)(w + 204800000);               //     400,384 (N+1)
    int*            cursor = (int*)(w + 205200384);               //     400,384
    int*            csr    = (int*)(w + 205600768);               //   6,400,000 -> 212,000,768
    unsigned short* Wqkvt  = (unsigned short*)(w + 212000768);    //     393,216 (768x256)
    unsigned short* Wot    = (unsigned short*)(w + 212393984);    //     131,072
    unsigned short* W1t    = (unsigned short*)(w + 212525056);    //     262,144
    unsigned short* W2t    = (unsigned short*)(w + 212787200);    //     262,144
    float*          bqkv   = (float*)(w + 213049344);             //       3,072 -> 213,052,416
    // aliases (temporally disjoint):
    unsigned short* hnewb  = hnormb;   // hnorm dead after QKV gemm
    unsigned short* h2nb   = hnormb;   // hnew dead after Wo gemm
    unsigned short* ffnmid = QKVb;     // QKV dead after attn (needs 102.4MB of 153.6MB)

    hipMemsetAsync(degoff, 0, 400384, stream);
    hipMemsetAsync(cursor, 0, 400384, stream);

    const int M = NN;
    dim3 blk(256);

    // weight conversion (transpose to [N][K] bf16); QKV concatenated row-wise
    wconv_k<<<dim3(8, 8),  blk, 0, stream>>>(Wq, Wqkvt,              256, 256);
    wconv_k<<<dim3(8, 8),  blk, 0, stream>>>(Wk, Wqkvt + 256 * 256, 256, 256);
    wconv_k<<<dim3(8, 8),  blk, 0, stream>>>(Wv, Wqkvt + 512 * 256, 256, 256);
    wconv_k<<<dim3(8, 8),  blk, 0, stream>>>(Wo, Wot, 256, 256);
    wconv_k<<<dim3(8, 16), blk, 0, stream>>>(W1, W1t, 256, 512);
    wconv_k<<<dim3(16, 8), blk, 0, stream>>>(W2, W2t, 512, 256);
    bcat_k<<<dim3(1), blk, 0, stream>>>(bq, bk, bv, bqkv);

    // CSR build (independent of LN/gemms)
    degcnt_k<<<dim3((NE + 255) / 256), blk, 0, stream>>>(dst, degoff, NE);
    scan_k<<<dim3(1), dim3(1024), 0, stream>>>(degoff, NN);
    scatter_k<<<dim3((NE + 255) / 256), blk, 0, stream>>>(dst, src, degoff, cursor, csr, NE);

    // 1. LN1 -> bf16
    ln_k<<<dim3((NN + 3) / 4), blk, 0, stream>>>(h, g1, be1, hnormb, NN);

    // 2. fused QKV gemm (bf16 out, [n][768])
    dim3 g6x((768 / 128), (M + 127) / 128);
    mgemm_k<true, false, false><<<g6x, blk, 0, stream>>>(hnormb, Wqkvt, bqkv, QKVb, nullptr, M, 768, 256, 768, 0);

    // 3. fused edge attention -> hnew (bf16)
    attn_k<<<dim3((NN + 3) / 4), blk, 0, stream>>>(csr, degoff, QKVb, hnewb);

    // 4. h_mid = hnew @ Wo + bo + h -> d_out (f32)
    dim3 g2x((256 / 128), (M + 127) / 128);
    mgemm_k<false, false, true><<<g2x, blk, 0, stream>>>(hnewb, Wot, bo, out, h, M, 256, 256, 256, 0);

    // 5. LN2 -> bf16
    ln_k<<<dim3((NN + 3) / 4), blk, 0, stream>>>(out, g2, be2, h2nb, NN);

    // 6. FFN
    dim3 g4x((512 / 128), (M + 127) / 128);
    mgemm_k<true, true, false><<<g4x, blk, 0, stream>>>(h2nb, W1t, b1, ffnmid, nullptr, M, 512, 256, 512, 0);
    mgemm_k<false, false, true><<<g2x, blk, 0, stream>>>(ffnmid, W2t, b2, out, out, M, 256, 512, 256, 0);
}

// Round 6
// 904.331 us; speedup vs baseline: 2.8786x; 1.1298x over previous
//
#include <hip/hip_runtime.h>
#include <hip/hip_bf16.h>

#define NN 100000
#define NE 1600000
// HID=256, HEADS=4, HEAD_DIM=64

typedef __attribute__((ext_vector_type(8))) short bf16x8;
typedef __attribute__((ext_vector_type(4))) float f32x4;
typedef __attribute__((ext_vector_type(2))) float f32x2;
typedef __attribute__((ext_vector_type(2))) unsigned int u32x2;

// ---------- helpers ----------
__device__ __forceinline__ float bf2f(unsigned short u) {
    union { unsigned int i; float f; } c; c.i = ((unsigned int)u) << 16; return c.f;
}
__device__ __forceinline__ unsigned short f2bf(float f) {
    union { float f; unsigned int i; } c; c.f = f;
    unsigned int lsb = (c.i >> 16) & 1u;
    c.i += 0x7FFFu + lsb;   // round-to-nearest-even
    return (unsigned short)(c.i >> 16);
}
__device__ __forceinline__ unsigned char f2fp8(float v) {
    return (unsigned char)(__builtin_amdgcn_cvt_pk_fp8_f32(v, v, 0, false) & 0xff);
}
__device__ __forceinline__ void gload_lds16(const void* g, void* l) {
    __builtin_amdgcn_global_load_lds(
        (const __attribute__((address_space(1))) void*)g,
        (__attribute__((address_space(3))) void*)l, 16, 0, 0);
}

// ---------- LayerNorm: 4 rows/block, 1 wave/row, bf16 out ----------
__global__ __launch_bounds__(256) void ln_k(
    const float* __restrict__ x, const float* __restrict__ g,
    const float* __restrict__ b, unsigned short* __restrict__ y, int nrows)
{
    int w = threadIdx.x >> 6, lane = threadIdx.x & 63;
    int row = blockIdx.x * 4 + w;
    if (row >= nrows) return;
    const float4 xv = *(const float4*)(x + (size_t)row * 256 + lane * 4);
    float s  = xv.x + xv.y + xv.z + xv.w;
    float sq = xv.x*xv.x + xv.y*xv.y + xv.z*xv.z + xv.w*xv.w;
    #pragma unroll
    for (int m = 1; m < 64; m <<= 1) {
        s  += __shfl_xor(s,  m);
        sq += __shfl_xor(sq, m);
    }
    float mu  = s * (1.0f / 256.0f);
    float var = sq * (1.0f / 256.0f) - mu * mu;
    float r = rsqrtf(var + 1e-5f);
    float4 gv = *(const float4*)(g + lane * 4);
    float4 bv = *(const float4*)(b + lane * 4);
    ushort4 o;
    o.x = f2bf((xv.x - mu) * r * gv.x + bv.x);
    o.y = f2bf((xv.y - mu) * r * gv.y + bv.y);
    o.z = f2bf((xv.z - mu) * r * gv.z + bv.z);
    o.w = f2bf((xv.w - mu) * r * gv.w + bv.w);
    *(ushort4*)(y + (size_t)row * 256 + lane * 4) = o;
}

// ---------- weight transpose + f32->bf16: Wt[n][k] = W[k][n] ----------
__global__ __launch_bounds__(256) void wconv_k(
    const float* __restrict__ W, unsigned short* __restrict__ Wt, int K, int N)
{
    __shared__ unsigned short tl[32][33];
    int bk = blockIdx.x * 32, bn = blockIdx.y * 32;
    int lx = threadIdx.x & 31, ly = threadIdx.x >> 5;   // ly 0..7
    #pragma unroll
    for (int r = 0; r < 32; r += 8)
        tl[ly + r][lx] = f2bf(W[(size_t)(bk + ly + r) * N + bn + lx]);
    __syncthreads();
    #pragma unroll
    for (int r = 0; r < 32; r += 8)
        Wt[(size_t)(bn + ly + r) * K + bk + lx] = tl[lx][ly + r];
}

// ---------- concat 3 bias vectors of 256 into one 768 ----------
__global__ void bcat_k(const float* __restrict__ a, const float* __restrict__ b,
                       const float* __restrict__ c, float* __restrict__ o)
{
    int t = threadIdx.x;
    o[t] = a[t]; o[256 + t] = b[t]; o[512 + t] = c[t];
}

// ---------- MFMA bf16 GEMM: C[M,N] = A[M,K] @ Wt[N,K]^T + bias (+res)(relu) ----------
// 128x128 tile, BK=32, 256 threads = 4 waves (2x2), each wave 64x64 = 4x4 frags 16x16
// OMODE: 0 = f32 out, 1 = bf16 out, 2 = QKV split (col<256 -> bf16 Q, col>=256 -> fp8 KV8)
template<int OMODE, bool RELU, bool RES>
__global__ __launch_bounds__(256) void mgemm_k(
    const unsigned short* __restrict__ A, const unsigned short* __restrict__ Wt,
    const float* __restrict__ bias, void* __restrict__ outv, void* __restrict__ out2,
    const float* __restrict__ res, int M, int N, int K, int ldc, int coloff)
{
    __shared__ __align__(16) unsigned short As[128 * 32];
    __shared__ __align__(16) unsigned short Bs[128 * 32];
    const int t = threadIdx.x;
    const int lane = t & 63;
    const int wid = t >> 6;
    const int wm = wid >> 1, wn = wid & 1;
    const int bm = blockIdx.y * 128, bn = blockIdx.x * 128;

    f32x4 acc[4][4] = {};

    const int li0 = t,       r0 = li0 >> 2, s0 = (li0 & 3) ^ (r0 & 3);
    const int li1 = 256 + t, r1 = li1 >> 2, s1 = (li1 & 3) ^ (r1 & 3);
    const size_t arow0 = (size_t)min(bm + r0, M - 1) * K;
    const size_t arow1 = (size_t)min(bm + r1, M - 1) * K;
    const size_t brow0 = (size_t)(bn + r0) * K;
    const size_t brow1 = (size_t)(bn + r1) * K;

    const int fr = lane & 15;       // row within fragment
    const int fs = lane >> 4;       // k-slot 0..3
    const int rslot = fs ^ (fr & 3);  // swizzled LDS slot

    for (int k0 = 0; k0 < K; k0 += 32) {
        gload_lds16(A  + arow0 + k0 + s0 * 8, As + li0 * 8);
        gload_lds16(A  + arow1 + k0 + s1 * 8, As + li1 * 8);
        gload_lds16(Wt + brow0 + k0 + s0 * 8, Bs + li0 * 8);
        gload_lds16(Wt + brow1 + k0 + s1 * 8, Bs + li1 * 8);
        __syncthreads();
        bf16x8 af[4], bfr[4];
        #pragma unroll
        for (int fm = 0; fm < 4; ++fm) {
            int ra = wm * 64 + fm * 16 + fr;
            af[fm] = *(const bf16x8*)&As[ra * 32 + rslot * 8];
        }
        #pragma unroll
        for (int fn = 0; fn < 4; ++fn) {
            int rb = wn * 64 + fn * 16 + fr;
            bfr[fn] = *(const bf16x8*)&Bs[rb * 32 + rslot * 8];
        }
        #pragma unroll
        for (int fm = 0; fm < 4; ++fm)
            #pragma unroll
            for (int fn = 0; fn < 4; ++fn)
                acc[fm][fn] = __builtin_amdgcn_mfma_f32_16x16x32_bf16(
                    af[fm], bfr[fn], acc[fm][fn], 0, 0, 0);
        __syncthreads();
    }

    // epilogue: C/D layout col=lane&15, row=(lane>>4)*4+i
    #pragma unroll
    for (int fn = 0; fn < 4; ++fn) {
        const int col = bn + wn * 64 + fn * 16 + (lane & 15);
        const float bv = bias[col];
        #pragma unroll
        for (int fm = 0; fm < 4; ++fm) {
            const int rowb = bm + wm * 64 + fm * 16 + (lane >> 4) * 4;
            #pragma unroll
            for (int i = 0; i < 4; ++i) {
                int row = rowb + i;
                if (row < M) {
                    float v = acc[fm][fn][i] + bv;
                    if (RES)  v += res[(size_t)row * N + col];
                    if (RELU) v = fmaxf(v, 0.f);
                    if (OMODE == 2) {
                        if (col < 256)
                            ((unsigned short*)outv)[(size_t)row * 256 + col] = f2bf(v);
                        else
                            ((unsigned char*)out2)[(size_t)row * 512 + (col - 256)] = f2fp8(v);
                    } else {
                        size_t oi = (size_t)row * ldc + coloff + col;
                        if (OMODE == 1) ((unsigned short*)outv)[oi] = f2bf(v);
                        else            ((float*)outv)[oi] = v;
                    }
                }
            }
        }
    }
}

// ---------- degree count ----------
__global__ void degcnt_k(const int* __restrict__ dst, int* __restrict__ deg, int E)
{
    int e = blockIdx.x * blockDim.x + threadIdx.x;
    if (e < E) atomicAdd(deg + dst[e], 1);
}

// ---------- single-block exclusive scan (in place), total at a[n] ----------
__global__ __launch_bounds__(1024) void scan_k(int* __restrict__ a, int n)
{
    __shared__ int wsum[16];
    __shared__ int carry;
    __shared__ int tot;
    int t = threadIdx.x, lane = t & 63, w = t >> 6;
    if (t == 0) carry = 0;
    __syncthreads();
    for (int base = 0; base < n; base += 1024) {
        int i = base + t;
        int v = (i < n) ? a[i] : 0;
        int s = v;
        #pragma unroll
        for (int d2 = 1; d2 < 64; d2 <<= 1) {
            int u = __shfl_up(s, d2);
            if (lane >= d2) s += u;
        }
        if (lane == 63) wsum[w] = s;
        __syncthreads();
        if (t == 0) {
            int run = 0;
            #pragma unroll
            for (int j = 0; j < 16; ++j) { int x = wsum[j]; wsum[j] = run; run += x; }
            tot = run;
        }
        __syncthreads();
        int excl = carry + wsum[w] + (s - v);
        if (i < n) a[i] = excl;
        __syncthreads();
        if (t == 0) carry += tot;
        __syncthreads();
    }
    if (threadIdx.x == 0) a[n] = carry;
}

// ---------- CSR scatter: csr[pos] = src ----------
__global__ void scatter_k(
    const int* __restrict__ dst, const int* __restrict__ srcarr,
    const int* __restrict__ off, int* __restrict__ cursor,
    int* __restrict__ csr, int E)
{
    int e = blockIdx.x * blockDim.x + threadIdx.x;
    if (e >= E) return;
    int d = dst[e];
    int pos = off[d] + atomicAdd(cursor + d, 1);
    csr[pos] = srcarr[e];
}

// ---------- fused edge attention: 1 wave / node, flat softmax, fp8 K/V ----------
// Q[n][256] bf16 ; KV8[n][512] bytes: K fp8 0-255 | V fp8 256-511
__global__ __launch_bounds__(256) void attn_k(
    const int* __restrict__ csr, const int* __restrict__ off,
    const unsigned short* __restrict__ Q, const unsigned char* __restrict__ KV8,
    unsigned short* __restrict__ hnew)
{
    int w = threadIdx.x >> 6, lane = threadIdx.x & 63;
    int n = blockIdx.x * 4 + w;
    if (n >= NN) return;
    int e0 = off[n], e1 = off[n + 1];

    // Q fragment (streamed once -> non-temporal); lane owns dims lane*4..+3
    u32x2 qr = __builtin_nontemporal_load((const u32x2*)(Q + (size_t)n * 256 + lane * 4));
    const float q0 = bf2f((unsigned short)(qr.x & 0xffff)) * 0.125f;
    const float q1 = bf2f((unsigned short)(qr.x >> 16))    * 0.125f;
    const float q2 = bf2f((unsigned short)(qr.y & 0xffff)) * 0.125f;
    const float q3 = bf2f((unsigned short)(qr.y >> 16))    * 0.125f;

    float s = 0.f;
    float a0 = 0.f, a1 = 0.f, a2 = 0.f, a3 = 0.f;

    int i = e0;
    for (; i + 7 < e1; i += 8) {
        int ns[8];
        #pragma unroll
        for (int j = 0; j < 8; ++j) ns[j] = csr[i + j];
        unsigned int kd[8], vd[8];
        #pragma unroll
        for (int j = 0; j < 8; ++j) {
            const unsigned char* r = KV8 + (size_t)ns[j] * 512 + lane * 4;
            kd[j] = *(const unsigned int*)r;
            vd[j] = *(const unsigned int*)(r + 256);
        }
        float l[8];
        #pragma unroll
        for (int j = 0; j < 8; ++j) {
            f32x2 ka = __builtin_amdgcn_cvt_pk_f32_fp8(kd[j], false);
            f32x2 kb = __builtin_amdgcn_cvt_pk_f32_fp8(kd[j], true);
            l[j] = q0 * ka.x + q1 * ka.y + q2 * kb.x + q3 * kb.y;
        }
        #pragma unroll
        for (int m2 = 1; m2 < 16; m2 <<= 1) {
            #pragma unroll
            for (int j = 0; j < 8; ++j) l[j] += __shfl_xor(l[j], m2);
        }
        #pragma unroll
        for (int j = 0; j < 8; ++j) {
            float p = __expf(l[j]);
            f32x2 va = __builtin_amdgcn_cvt_pk_f32_fp8(vd[j], false);
            f32x2 vb = __builtin_amdgcn_cvt_pk_f32_fp8(vd[j], true);
            s  += p;
            a0 += p * va.x; a1 += p * va.y;
            a2 += p * vb.x; a3 += p * vb.y;
        }
    }
    for (; i + 3 < e1; i += 4) {
        int ns[4];
        #pragma unroll
        for (int j = 0; j < 4; ++j) ns[j] = csr[i + j];
        unsigned int kd[4], vd[4];
        #pragma unroll
        for (int j = 0; j < 4; ++j) {
            const unsigned char* r = KV8 + (size_t)ns[j] * 512 + lane * 4;
            kd[j] = *(const unsigned int*)r;
            vd[j] = *(const unsigned int*)(r + 256);
        }
        float l[4];
        #pragma unroll
        for (int j = 0; j < 4; ++j) {
            f32x2 ka = __builtin_amdgcn_cvt_pk_f32_fp8(kd[j], false);
            f32x2 kb = __builtin_amdgcn_cvt_pk_f32_fp8(kd[j], true);
            l[j] = q0 * ka.x + q1 * ka.y + q2 * kb.x + q3 * kb.y;
        }
        #pragma unroll
        for (int m2 = 1; m2 < 16; m2 <<= 1) {
            #pragma unroll
            for (int j = 0; j < 4; ++j) l[j] += __shfl_xor(l[j], m2);
        }
        #pragma unroll
        for (int j = 0; j < 4; ++j) {
            float p = __expf(l[j]);
            f32x2 va = __builtin_amdgcn_cvt_pk_f32_fp8(vd[j], false);
            f32x2 vb = __builtin_amdgcn_cvt_pk_f32_fp8(vd[j], true);
            s  += p;
            a0 += p * va.x; a1 += p * va.y;
            a2 += p * vb.x; a3 += p * vb.y;
        }
    }
    for (; i < e1; ++i) {
        int n0 = csr[i];
        const unsigned char* r = KV8 + (size_t)n0 * 512 + lane * 4;
        unsigned int kd = *(const unsigned int*)r;
        unsigned int vd = *(const unsigned int*)(r + 256);
        f32x2 ka = __builtin_amdgcn_cvt_pk_f32_fp8(kd, false);
        f32x2 kb = __builtin_amdgcn_cvt_pk_f32_fp8(kd, true);
        float l0 = q0 * ka.x + q1 * ka.y + q2 * kb.x + q3 * kb.y;
        #pragma unroll
        for (int m2 = 1; m2 < 16; m2 <<= 1) l0 += __shfl_xor(l0, m2);
        float p = __expf(l0);
        f32x2 va = __builtin_amdgcn_cvt_pk_f32_fp8(vd, false);
        f32x2 vb = __builtin_amdgcn_cvt_pk_f32_fp8(vd, true);
        s  += p;
        a0 += p * va.x; a1 += p * va.y;
        a2 += p * vb.x; a3 += p * vb.y;
    }
    float inv = (e1 > e0) ? 1.0f / s : 0.f;
    u32x2 ov;
    ov.x = ((unsigned int)f2bf(a1 * inv) << 16) | f2bf(a0 * inv);
    ov.y = ((unsigned int)f2bf(a3 * inv) << 16) | f2bf(a2 * inv);
    __builtin_nontemporal_store(ov, (u32x2*)(hnew + (size_t)n * 256 + lane * 4));
}

// ---------- host ----------
extern "C" void kernel_launch(void* const* d_in, const int* in_sizes, int n_in,
                              void* d_out, int out_size, void* d_ws, size_t ws_size,
                              hipStream_t stream)
{
    if (n_in < 19) return;
    const float* h   = (const float*)d_in[0];
    const int*   src = (const int*)d_in[1];
    const int*   dst = (const int*)d_in[2];
    const float* Wq  = (const float*)d_in[3];
    const float* bq  = (const float*)d_in[4];
    const float* Wk  = (const float*)d_in[5];
    const float* bk  = (const float*)d_in[6];
    const float* Wv  = (const float*)d_in[7];
    const float* bv  = (const float*)d_in[8];
    const float* Wo  = (const float*)d_in[9];
    const float* bo  = (const float*)d_in[10];
    const float* W1  = (const float*)d_in[11];
    const float* b1  = (const float*)d_in[12];
    const float* W2  = (const float*)d_in[13];
    const float* b2  = (const float*)d_in[14];
    const float* g1  = (const float*)d_in[15];
    const float* be1 = (const float*)d_in[16];
    const float* g2  = (const float*)d_in[17];
    const float* be2 = (const float*)d_in[18];
    float* out = (float*)d_out;

    char* w = (char*)d_ws;
    // layout (bytes):
    unsigned short* hnormb = (unsigned short*)(w + 0);            //  51,200,000
    unsigned short* Qb     = (unsigned short*)(w + 51200000);     //  51,200,000
    unsigned char*  KV8    = (unsigned char*)(w + 102400000);     //  51,200,000 (fp8 K|V)
    int*            degoff = (int*)(w + 153600000);               //     400,384 (N+1)
    int*            cursor = (int*)(w + 154000384);               //     400,384
    int*            csr    = (int*)(w + 154400768);               //   6,400,000 -> 160,800,768
    unsigned short* Wqkvt  = (unsigned short*)(w + 160800768);    //     393,216 (768x256)
    unsigned short* Wot    = (unsigned short*)(w + 161193984);    //     131,072
    unsigned short* W1t    = (unsigned short*)(w + 161325056);    //     262,144
    unsigned short* W2t    = (unsigned short*)(w + 161587200);    //     262,144
    float*          bqkv   = (float*)(w + 161849344);             //       3,072 -> 161,852,416
    // aliases (temporally disjoint):
    unsigned short* hnewb  = hnormb;                       // hnorm dead after QKV gemm
    unsigned short* h2nb   = hnormb;                       // hnew dead after Wo gemm
    unsigned short* ffnmid = (unsigned short*)(w + 51200000); // Qb+KV8 dead after attn (102.4MB)

    hipMemsetAsync(degoff, 0, 400384, stream);
    hipMemsetAsync(cursor, 0, 400384, stream);

    const int M = NN;
    dim3 blk(256);

    // weight conversion (transpose to [N][K] bf16); QKV concatenated row-wise
    wconv_k<<<dim3(8, 8),  blk, 0, stream>>>(Wq, Wqkvt,             256, 256);
    wconv_k<<<dim3(8, 8),  blk, 0, stream>>>(Wk, Wqkvt + 256 * 256, 256, 256);
    wconv_k<<<dim3(8, 8),  blk, 0, stream>>>(Wv, Wqkvt + 512 * 256, 256, 256);
    wconv_k<<<dim3(8, 8),  blk, 0, stream>>>(Wo, Wot, 256, 256);
    wconv_k<<<dim3(8, 16), blk, 0, stream>>>(W1, W1t, 256, 512);
    wconv_k<<<dim3(16, 8), blk, 0, stream>>>(W2, W2t, 512, 256);
    bcat_k<<<dim3(1), blk, 0, stream>>>(bq, bk, bv, bqkv);

    // CSR build (independent of LN/gemms)
    degcnt_k<<<dim3((NE + 255) / 256), blk, 0, stream>>>(dst, degoff, NE);
    scan_k<<<dim3(1), dim3(1024), 0, stream>>>(degoff, NN);
    scatter_k<<<dim3((NE + 255) / 256), blk, 0, stream>>>(dst, src, degoff, cursor, csr, NE);

    // 1. LN1 -> bf16
    ln_k<<<dim3((NN + 3) / 4), blk, 0, stream>>>(h, g1, be1, hnormb, NN);

    // 2. fused QKV gemm: Q bf16, K/V fp8
    dim3 g6x((768 / 128), (M + 127) / 128);
    mgemm_k<2, false, false><<<g6x, blk, 0, stream>>>(hnormb, Wqkvt, bqkv, Qb, KV8, nullptr, M, 768, 256, 0, 0);

    // 3. fused edge attention -> hnew (bf16)
    attn_k<<<dim3((NN + 3) / 4), blk, 0, stream>>>(csr, degoff, Qb, KV8, hnewb);

    // 4. h_mid = hnew @ Wo + bo + h -> d_out (f32)
    dim3 g2x((256 / 128), (M + 127) / 128);
    mgemm_k<0, false, true><<<g2x, blk, 0, stream>>>(hnewb, Wot, bo, out, nullptr, h, M, 256, 256, 256, 0);

    // 5. LN2 -> bf16
    ln_k<<<dim3((NN + 3) / 4), blk, 0, stream>>>(out, g2, be2, h2nb, NN);

    // 6. FFN
    dim3 g4x((512 / 128), (M + 127) / 128);
    mgemm_k<1, true, false><<<g4x, blk, 0, stream>>>(h2nb, W1t, b1, ffnmid, nullptr, nullptr, M, 512, 256, 512, 0);
    mgemm_k<0, false, true><<<g2x, blk, 0, stream>>>(ffnmid, W2t, b2, out, nullptr, out, M, 256, 512, 256, 0);
}

// Round 7
// 701.626 us; speedup vs baseline: 3.7103x; 1.2889x over previous
//
#include <hip/hip_runtime.h>
#include <hip/hip_bf16.h>

#define NN 100000
#define NE 1600000
// HID=256, HEADS=4, HEAD_DIM=64

typedef __attribute__((ext_vector_type(8))) short bf16x8;
typedef __attribute__((ext_vector_type(4))) float f32x4;
typedef __attribute__((ext_vector_type(2))) float f32x2;
typedef __attribute__((ext_vector_type(2))) unsigned int u32x2;
typedef __attribute__((ext_vector_type(4))) unsigned int u32x4;

// ---------- helpers ----------
__device__ __forceinline__ float bf2f(unsigned short u) {
    union { unsigned int i; float f; } c; c.i = ((unsigned int)u) << 16; return c.f;
}
__device__ __forceinline__ unsigned short f2bf(float f) {
    union { float f; unsigned int i; } c; c.f = f;
    unsigned int lsb = (c.i >> 16) & 1u;
    c.i += 0x7FFFu + lsb;   // round-to-nearest-even
    return (unsigned short)(c.i >> 16);
}
__device__ __forceinline__ unsigned char f2fp8(float v) {
    return (unsigned char)(__builtin_amdgcn_cvt_pk_fp8_f32(v, v, 0, false) & 0xff);
}
__device__ __forceinline__ void gload_lds16(const void* g, void* l) {
    __builtin_amdgcn_global_load_lds(
        (const __attribute__((address_space(1))) void*)g,
        (__attribute__((address_space(3))) void*)l, 16, 0, 0);
}

// ---------- LayerNorm: 4 rows/block, 1 wave/row, bf16 out ----------
__global__ __launch_bounds__(256) void ln_k(
    const float* __restrict__ x, const float* __restrict__ g,
    const float* __restrict__ b, unsigned short* __restrict__ y, int nrows)
{
    int w = threadIdx.x >> 6, lane = threadIdx.x & 63;
    int row = blockIdx.x * 4 + w;
    if (row >= nrows) return;
    const float4 xv = *(const float4*)(x + (size_t)row * 256 + lane * 4);
    float s  = xv.x + xv.y + xv.z + xv.w;
    float sq = xv.x*xv.x + xv.y*xv.y + xv.z*xv.z + xv.w*xv.w;
    #pragma unroll
    for (int m = 1; m < 64; m <<= 1) {
        s  += __shfl_xor(s,  m);
        sq += __shfl_xor(sq, m);
    }
    float mu  = s * (1.0f / 256.0f);
    float var = sq * (1.0f / 256.0f) - mu * mu;
    float r = rsqrtf(var + 1e-5f);
    float4 gv = *(const float4*)(g + lane * 4);
    float4 bv = *(const float4*)(b + lane * 4);
    ushort4 o;
    o.x = f2bf((xv.x - mu) * r * gv.x + bv.x);
    o.y = f2bf((xv.y - mu) * r * gv.y + bv.y);
    o.z = f2bf((xv.z - mu) * r * gv.z + bv.z);
    o.w = f2bf((xv.w - mu) * r * gv.w + bv.w);
    *(ushort4*)(y + (size_t)row * 256 + lane * 4) = o;
}

// ---------- weight transpose + f32->bf16: Wt[n][k] = W[k][n] ----------
__global__ __launch_bounds__(256) void wconv_k(
    const float* __restrict__ W, unsigned short* __restrict__ Wt, int K, int N)
{
    __shared__ unsigned short tl[32][33];
    int bk = blockIdx.x * 32, bn = blockIdx.y * 32;
    int lx = threadIdx.x & 31, ly = threadIdx.x >> 5;   // ly 0..7
    #pragma unroll
    for (int r = 0; r < 32; r += 8)
        tl[ly + r][lx] = f2bf(W[(size_t)(bk + ly + r) * N + bn + lx]);
    __syncthreads();
    #pragma unroll
    for (int r = 0; r < 32; r += 8)
        Wt[(size_t)(bn + ly + r) * K + bk + lx] = tl[lx][ly + r];
}

// ---------- concat 3 bias vectors of 256 into one 768 ----------
__global__ void bcat_k(const float* __restrict__ a, const float* __restrict__ b,
                       const float* __restrict__ c, float* __restrict__ o)
{
    int t = threadIdx.x;
    o[t] = a[t]; o[256 + t] = b[t]; o[512 + t] = c[t];
}

// ---------- MFMA bf16 GEMM v2: C[M,N] = A[M,K] @ Wt[N,K]^T + bias (+res)(relu) ----------
// 128x256 tile, BK=32 double-buffered, 512 threads = 8 waves (2Mx4N), wave = 64x64
// OMODE: 0 = f32 out, 1 = bf16 out, 2 = QKV split (col<256 -> bf16 Q, col>=256 -> fp8 KV8)
template<int OMODE, bool RELU, bool RES>
__global__ __launch_bounds__(512) void mgemm_k(
    const unsigned short* __restrict__ A, const unsigned short* __restrict__ Wt,
    const float* __restrict__ bias, void* __restrict__ outv, void* __restrict__ out2,
    const float* __restrict__ res, int M, int N, int K)
{
    __shared__ __align__(16) char lds[49152];   // A dbuf 2x8KB @0, B dbuf 2x16KB @16384
    const int t = threadIdx.x;
    const int lane = t & 63;
    const int wid = t >> 6;                 // 0..7
    const int wm = wid >> 2, wn = wid & 3;  // 2 x 4
    const int bm = blockIdx.y * 128, bn = blockIdx.x * 256;

    f32x4 acc[4][4] = {};

    // staging indices (gload_lds: wave-uniform LDS base + lane*16)
    const int ra_s = t >> 2;                       // A row 0..127
    const int sa_s = (t & 3) ^ (ra_s & 3);         // XOR-swizzled k-slot
    const size_t arow = (size_t)min(bm + ra_s, M - 1) * K + sa_s * 8;
    const int rb0 = t >> 2;                        // B rows 0..127
    const int sb0 = (t & 3) ^ (rb0 & 3);
    const int rb1 = (512 + t) >> 2;                // B rows 128..255
    const int sb1 = (t & 3) ^ (rb1 & 3);
    const size_t brow0 = (size_t)(bn + rb0) * K + sb0 * 8;
    const size_t brow1 = (size_t)(bn + rb1) * K + sb1 * 8;

    const int fr = lane & 15, fs = lane >> 4;
    const int rslot = fs ^ (fr & 3);

    const int KS = K >> 5;
    int cur = 0;
    // prologue: stage k-step 0 into buf 0
    {
        unsigned short* Ab = (unsigned short*)(lds);
        unsigned short* Bb = (unsigned short*)(lds + 16384);
        gload_lds16(A + arow, Ab + t * 8);
        gload_lds16(Wt + brow0, Bb + t * 8);
        gload_lds16(Wt + brow1, Bb + (512 + t) * 8);
    }
    for (int ks = 0; ks < KS; ++ks) {
        __syncthreads();   // drains vmcnt -> buf[cur] staged data visible
        if (ks + 1 < KS) {
            int k1 = (ks + 1) << 5;
            unsigned short* Ab = (unsigned short*)(lds + (cur ^ 1) * 8192);
            unsigned short* Bb = (unsigned short*)(lds + 16384 + (cur ^ 1) * 16384);
            gload_lds16(A + arow + k1, Ab + t * 8);
            gload_lds16(Wt + brow0 + k1, Bb + t * 8);
            gload_lds16(Wt + brow1 + k1, Bb + (512 + t) * 8);
        }
        const unsigned short* As = (const unsigned short*)(lds + cur * 8192);
        const unsigned short* Bs = (const unsigned short*)(lds + 16384 + cur * 16384);
        bf16x8 af[4], bf[4];
        #pragma unroll
        for (int fm = 0; fm < 4; ++fm)
            af[fm] = *(const bf16x8*)&As[(wm * 64 + fm * 16 + fr) * 32 + rslot * 8];
        #pragma unroll
        for (int fn = 0; fn < 4; ++fn)
            bf[fn] = *(const bf16x8*)&Bs[(wn * 64 + fn * 16 + fr) * 32 + rslot * 8];
        #pragma unroll
        for (int fm = 0; fm < 4; ++fm)
            #pragma unroll
            for (int fn = 0; fn < 4; ++fn)
                acc[fm][fn] = __builtin_amdgcn_mfma_f32_16x16x32_bf16(
                    af[fm], bf[fn], acc[fm][fn], 0, 0, 0);
        cur ^= 1;
    }
    __syncthreads();   // staging LDS now dead; reuse for epilogue transpose

    // epilogue: per-wave LDS bounce [16 rows][68 stride f32], then wide stores
    float* wl = (float*)(lds + wid * 4352);
    const int rr = lane >> 2;               // row 0..15 within fm stripe
    const int c4 = (lane & 3) * 16;         // 16-col chunk
    const int qg = lane >> 4;               // quad group for C-layout rows
    #pragma unroll
    for (int fm = 0; fm < 4; ++fm) {
        #pragma unroll
        for (int fn = 0; fn < 4; ++fn)
            #pragma unroll
            for (int i = 0; i < 4; ++i)
                wl[(qg * 4 + i) * 68 + fn * 16 + fr] = acc[fm][fn][i];
        f32x4 v0 = *(const f32x4*)&wl[rr * 68 + c4 + 0];
        f32x4 v1 = *(const f32x4*)&wl[rr * 68 + c4 + 4];
        f32x4 v2 = *(const f32x4*)&wl[rr * 68 + c4 + 8];
        f32x4 v3 = *(const f32x4*)&wl[rr * 68 + c4 + 12];
        const int rowg = bm + wm * 64 + fm * 16 + rr;
        const int colg = bn + wn * 64 + c4;
        if (rowg < M) {
            f32x4 b0 = *(const f32x4*)&bias[colg + 0];
            f32x4 b1 = *(const f32x4*)&bias[colg + 4];
            f32x4 b2 = *(const f32x4*)&bias[colg + 8];
            f32x4 b3 = *(const f32x4*)&bias[colg + 12];
            v0 += b0; v1 += b1; v2 += b2; v3 += b3;
            if (RES) {
                const float* rp = res + (size_t)rowg * N + colg;
                v0 += *(const f32x4*)(rp + 0);
                v1 += *(const f32x4*)(rp + 4);
                v2 += *(const f32x4*)(rp + 8);
                v3 += *(const f32x4*)(rp + 12);
            }
            if (RELU) {
                #pragma unroll
                for (int j = 0; j < 4; ++j) {
                    v0[j] = fmaxf(v0[j], 0.f); v1[j] = fmaxf(v1[j], 0.f);
                    v2[j] = fmaxf(v2[j], 0.f); v3[j] = fmaxf(v3[j], 0.f);
                }
            }
            if (OMODE == 0) {
                float* op = (float*)outv + (size_t)rowg * N + colg;
                *(f32x4*)(op + 0) = v0; *(f32x4*)(op + 4) = v1;
                *(f32x4*)(op + 8) = v2; *(f32x4*)(op + 12) = v3;
            } else if (OMODE == 1) {
                unsigned short* op = (unsigned short*)outv + (size_t)rowg * N + colg;
                u32x4 pa, pb;
                pa.x = f2bf(v0[0]) | ((unsigned int)f2bf(v0[1]) << 16);
                pa.y = f2bf(v0[2]) | ((unsigned int)f2bf(v0[3]) << 16);
                pa.z = f2bf(v1[0]) | ((unsigned int)f2bf(v1[1]) << 16);
                pa.w = f2bf(v1[2]) | ((unsigned int)f2bf(v1[3]) << 16);
                pb.x = f2bf(v2[0]) | ((unsigned int)f2bf(v2[1]) << 16);
                pb.y = f2bf(v2[2]) | ((unsigned int)f2bf(v2[3]) << 16);
                pb.z = f2bf(v3[0]) | ((unsigned int)f2bf(v3[1]) << 16);
                pb.w = f2bf(v3[2]) | ((unsigned int)f2bf(v3[3]) << 16);
                *(u32x4*)(op + 0) = pa;
                *(u32x4*)(op + 8) = pb;
            } else {
                if (colg < 256) {   // Q -> bf16 [n][256]
                    unsigned short* op = (unsigned short*)outv + (size_t)rowg * 256 + colg;
                    u32x4 pa, pb;
                    pa.x = f2bf(v0[0]) | ((unsigned int)f2bf(v0[1]) << 16);
                    pa.y = f2bf(v0[2]) | ((unsigned int)f2bf(v0[3]) << 16);
                    pa.z = f2bf(v1[0]) | ((unsigned int)f2bf(v1[1]) << 16);
                    pa.w = f2bf(v1[2]) | ((unsigned int)f2bf(v1[3]) << 16);
                    pb.x = f2bf(v2[0]) | ((unsigned int)f2bf(v2[1]) << 16);
                    pb.y = f2bf(v2[2]) | ((unsigned int)f2bf(v2[3]) << 16);
                    pb.z = f2bf(v3[0]) | ((unsigned int)f2bf(v3[1]) << 16);
                    pb.w = f2bf(v3[2]) | ((unsigned int)f2bf(v3[3]) << 16);
                    *(u32x4*)(op + 0) = pa;
                    *(u32x4*)(op + 8) = pb;
                } else {            // K/V -> fp8 [n][512]B, K at 0-255, V at 256-511
                    u32x4 p8;
                    unsigned int w0, w1, w2, w3;
                    w0 = __builtin_amdgcn_cvt_pk_fp8_f32(v0[0], v0[1], 0, false);
                    w0 = __builtin_amdgcn_cvt_pk_fp8_f32(v0[2], v0[3], w0, true);
                    w1 = __builtin_amdgcn_cvt_pk_fp8_f32(v1[0], v1[1], 0, false);
                    w1 = __builtin_amdgcn_cvt_pk_fp8_f32(v1[2], v1[3], w1, true);
                    w2 = __builtin_amdgcn_cvt_pk_fp8_f32(v2[0], v2[1], 0, false);
                    w2 = __builtin_amdgcn_cvt_pk_fp8_f32(v2[2], v2[3], w2, true);
                    w3 = __builtin_amdgcn_cvt_pk_fp8_f32(v3[0], v3[1], 0, false);
                    w3 = __builtin_amdgcn_cvt_pk_fp8_f32(v3[2], v3[3], w3, true);
                    p8.x = w0; p8.y = w1; p8.z = w2; p8.w = w3;
                    *(u32x4*)((unsigned char*)out2 + (size_t)rowg * 512 + (colg - 256)) = p8;
                }
            }
        }
    }
}

// ---------- degree count ----------
__global__ void degcnt_k(const int* __restrict__ dst, int* __restrict__ deg, int E)
{
    int e = blockIdx.x * blockDim.x + threadIdx.x;
    if (e < E) atomicAdd(deg + dst[e], 1);
}

// ---------- single-block exclusive scan (in place), total at a[n] ----------
__global__ __launch_bounds__(1024) void scan_k(int* __restrict__ a, int n)
{
    __shared__ int wsum[16];
    __shared__ int carry;
    __shared__ int tot;
    int t = threadIdx.x, lane = t & 63, w = t >> 6;
    if (t == 0) carry = 0;
    __syncthreads();
    for (int base = 0; base < n; base += 1024) {
        int i = base + t;
        int v = (i < n) ? a[i] : 0;
        int s = v;
        #pragma unroll
        for (int d2 = 1; d2 < 64; d2 <<= 1) {
            int u = __shfl_up(s, d2);
            if (lane >= d2) s += u;
        }
        if (lane == 63) wsum[w] = s;
        __syncthreads();
        if (t == 0) {
            int run = 0;
            #pragma unroll
            for (int j = 0; j < 16; ++j) { int x = wsum[j]; wsum[j] = run; run += x; }
            tot = run;
        }
        __syncthreads();
        int excl = carry + wsum[w] + (s - v);
        if (i < n) a[i] = excl;
        __syncthreads();
        if (t == 0) carry += tot;
        __syncthreads();
    }
    if (threadIdx.x == 0) a[n] = carry;
}

// ---------- CSR scatter: csr[pos] = src ----------
__global__ void scatter_k(
    const int* __restrict__ dst, const int* __restrict__ srcarr,
    const int* __restrict__ off, int* __restrict__ cursor,
    int* __restrict__ csr, int E)
{
    int e = blockIdx.x * blockDim.x + threadIdx.x;
    if (e >= E) return;
    int d = dst[e];
    int pos = off[d] + atomicAdd(cursor + d, 1);
    csr[pos] = srcarr[e];
}

// ---------- fused edge attention: 1 wave / node, flat softmax, fp8 K/V ----------
// Q[n][256] bf16 ; KV8[n][512] bytes: K fp8 0-255 | V fp8 256-511
__global__ __launch_bounds__(256) void attn_k(
    const int* __restrict__ csr, const int* __restrict__ off,
    const unsigned short* __restrict__ Q, const unsigned char* __restrict__ KV8,
    unsigned short* __restrict__ hnew)
{
    int w = threadIdx.x >> 6, lane = threadIdx.x & 63;
    int n = blockIdx.x * 4 + w;
    if (n >= NN) return;
    int e0 = off[n], e1 = off[n + 1];

    // Q fragment (streamed once -> non-temporal); lane owns dims lane*4..+3
    u32x2 qr = __builtin_nontemporal_load((const u32x2*)(Q + (size_t)n * 256 + lane * 4));
    const float q0 = bf2f((unsigned short)(qr.x & 0xffff)) * 0.125f;
    const float q1 = bf2f((unsigned short)(qr.x >> 16))    * 0.125f;
    const float q2 = bf2f((unsigned short)(qr.y & 0xffff)) * 0.125f;
    const float q3 = bf2f((unsigned short)(qr.y >> 16))    * 0.125f;

    float s = 0.f;
    float a0 = 0.f, a1 = 0.f, a2 = 0.f, a3 = 0.f;

    int i = e0;
    for (; i + 7 < e1; i += 8) {
        int ns[8];
        #pragma unroll
        for (int j = 0; j < 8; ++j) ns[j] = csr[i + j];
        unsigned int kd[8], vd[8];
        #pragma unroll
        for (int j = 0; j < 8; ++j) {
            const unsigned char* r = KV8 + (size_t)ns[j] * 512 + lane * 4;
            kd[j] = *(const unsigned int*)r;
            vd[j] = *(const unsigned int*)(r + 256);
        }
        float l[8];
        #pragma unroll
        for (int j = 0; j < 8; ++j) {
            f32x2 ka = __builtin_amdgcn_cvt_pk_f32_fp8(kd[j], false);
            f32x2 kb = __builtin_amdgcn_cvt_pk_f32_fp8(kd[j], true);
            l[j] = q0 * ka.x + q1 * ka.y + q2 * kb.x + q3 * kb.y;
        }
        #pragma unroll
        for (int m2 = 1; m2 < 16; m2 <<= 1) {
            #pragma unroll
            for (int j = 0; j < 8; ++j) l[j] += __shfl_xor(l[j], m2);
        }
        #pragma unroll
        for (int j = 0; j < 8; ++j) {
            float p = __expf(l[j]);
            f32x2 va = __builtin_amdgcn_cvt_pk_f32_fp8(vd[j], false);
            f32x2 vb = __builtin_amdgcn_cvt_pk_f32_fp8(vd[j], true);
            s  += p;
            a0 += p * va.x; a1 += p * va.y;
            a2 += p * vb.x; a3 += p * vb.y;
        }
    }
    for (; i + 3 < e1; i += 4) {
        int ns[4];
        #pragma unroll
        for (int j = 0; j < 4; ++j) ns[j] = csr[i + j];
        unsigned int kd[4], vd[4];
        #pragma unroll
        for (int j = 0; j < 4; ++j) {
            const unsigned char* r = KV8 + (size_t)ns[j] * 512 + lane * 4;
            kd[j] = *(const unsigned int*)r;
            vd[j] = *(const unsigned int*)(r + 256);
        }
        float l[4];
        #pragma unroll
        for (int j = 0; j < 4; ++j) {
            f32x2 ka = __builtin_amdgcn_cvt_pk_f32_fp8(kd[j], false);
            f32x2 kb = __builtin_amdgcn_cvt_pk_f32_fp8(kd[j], true);
            l[j] = q0 * ka.x + q1 * ka.y + q2 * kb.x + q3 * kb.y;
        }
        #pragma unroll
        for (int m2 = 1; m2 < 16; m2 <<= 1) {
            #pragma unroll
            for (int j = 0; j < 4; ++j) l[j] += __shfl_xor(l[j], m2);
        }
        #pragma unroll
        for (int j = 0; j < 4; ++j) {
            float p = __expf(l[j]);
            f32x2 va = __builtin_amdgcn_cvt_pk_f32_fp8(vd[j], false);
            f32x2 vb = __builtin_amdgcn_cvt_pk_f32_fp8(vd[j], true);
            s  += p;
            a0 += p * va.x; a1 += p * va.y;
            a2 += p * vb.x; a3 += p * vb.y;
        }
    }
    for (; i < e1; ++i) {
        int n0 = csr[i];
        const unsigned char* r = KV8 + (size_t)n0 * 512 + lane * 4;
        unsigned int kd = *(const unsigned int*)r;
        unsigned int vd = *(const unsigned int*)(r + 256);
        f32x2 ka = __builtin_amdgcn_cvt_pk_f32_fp8(kd, false);
        f32x2 kb = __builtin_amdgcn_cvt_pk_f32_fp8(kd, true);
        float l0 = q0 * ka.x + q1 * ka.y + q2 * kb.x + q3 * kb.y;
        #pragma unroll
        for (int m2 = 1; m2 < 16; m2 <<= 1) l0 += __shfl_xor(l0, m2);
        float p = __expf(l0);
        f32x2 va = __builtin_amdgcn_cvt_pk_f32_fp8(vd, false);
        f32x2 vb = __builtin_amdgcn_cvt_pk_f32_fp8(vd, true);
        s  += p;
        a0 += p * va.x; a1 += p * va.y;
        a2 += p * vb.x; a3 += p * vb.y;
    }
    float inv = (e1 > e0) ? 1.0f / s : 0.f;
    u32x2 ov;
    ov.x = ((unsigned int)f2bf(a1 * inv) << 16) | f2bf(a0 * inv);
    ov.y = ((unsigned int)f2bf(a3 * inv) << 16) | f2bf(a2 * inv);
    __builtin_nontemporal_store(ov, (u32x2*)(hnew + (size_t)n * 256 + lane * 4));
}

// ---------- host ----------
extern "C" void kernel_launch(void* const* d_in, const int* in_sizes, int n_in,
                              void* d_out, int out_size, void* d_ws, size_t ws_size,
                              hipStream_t stream)
{
    if (n_in < 19) return;
    const float* h   = (const float*)d_in[0];
    const int*   src = (const int*)d_in[1];
    const int*   dst = (const int*)d_in[2];
    const float* Wq  = (const float*)d_in[3];
    const float* bq  = (const float*)d_in[4];
    const float* Wk  = (const float*)d_in[5];
    const float* bk  = (const float*)d_in[6];
    const float* Wv  = (const float*)d_in[7];
    const float* bv  = (const float*)d_in[8];
    const float* Wo  = (const float*)d_in[9];
    const float* bo  = (const float*)d_in[10];
    const float* W1  = (const float*)d_in[11];
    const float* b1  = (const float*)d_in[12];
    const float* W2  = (const float*)d_in[13];
    const float* b2  = (const float*)d_in[14];
    const float* g1  = (const float*)d_in[15];
    const float* be1 = (const float*)d_in[16];
    const float* g2  = (const float*)d_in[17];
    const float* be2 = (const float*)d_in[18];
    float* out = (float*)d_out;

    char* w = (char*)d_ws;
    // layout (bytes):
    unsigned short* hnormb = (unsigned short*)(w + 0);            //  51,200,000
    unsigned short* Qb     = (unsigned short*)(w + 51200000);     //  51,200,000
    unsigned char*  KV8    = (unsigned char*)(w + 102400000);     //  51,200,000 (fp8 K|V)
    int*            degoff = (int*)(w + 153600000);               //     400,384 (N+1)
    int*            cursor = (int*)(w + 154000384);               //     400,384
    int*            csr    = (int*)(w + 154400768);               //   6,400,000 -> 160,800,768
    unsigned short* Wqkvt  = (unsigned short*)(w + 160800768);    //     393,216 (768x256)
    unsigned short* Wot    = (unsigned short*)(w + 161193984);    //     131,072
    unsigned short* W1t    = (unsigned short*)(w + 161325056);    //     262,144
    unsigned short* W2t    = (unsigned short*)(w + 161587200);    //     262,144
    float*          bqkv   = (float*)(w + 161849344);             //       3,072 -> 161,852,416
    // aliases (temporally disjoint):
    unsigned short* hnewb  = hnormb;                       // hnorm dead after QKV gemm
    unsigned short* h2nb   = hnormb;                       // hnew dead after Wo gemm
    unsigned short* ffnmid = (unsigned short*)(w + 51200000); // Qb+KV8 dead after attn (102.4MB)

    hipMemsetAsync(degoff, 0, 400384, stream);
    hipMemsetAsync(cursor, 0, 400384, stream);

    const int M = NN;
    dim3 blk(256);
    dim3 blk512(512);

    // weight conversion (transpose to [N][K] bf16); QKV concatenated row-wise
    wconv_k<<<dim3(8, 8),  blk, 0, stream>>>(Wq, Wqkvt,             256, 256);
    wconv_k<<<dim3(8, 8),  blk, 0, stream>>>(Wk, Wqkvt + 256 * 256, 256, 256);
    wconv_k<<<dim3(8, 8),  blk, 0, stream>>>(Wv, Wqkvt + 512 * 256, 256, 256);
    wconv_k<<<dim3(8, 8),  blk, 0, stream>>>(Wo, Wot, 256, 256);
    wconv_k<<<dim3(8, 16), blk, 0, stream>>>(W1, W1t, 256, 512);
    wconv_k<<<dim3(16, 8), blk, 0, stream>>>(W2, W2t, 512, 256);
    bcat_k<<<dim3(1), blk, 0, stream>>>(bq, bk, bv, bqkv);

    // CSR build (independent of LN/gemms)
    degcnt_k<<<dim3((NE + 255) / 256), blk, 0, stream>>>(dst, degoff, NE);
    scan_k<<<dim3(1), dim3(1024), 0, stream>>>(degoff, NN);
    scatter_k<<<dim3((NE + 255) / 256), blk, 0, stream>>>(dst, src, degoff, cursor, csr, NE);

    // 1. LN1 -> bf16
    ln_k<<<dim3((NN + 3) / 4), blk, 0, stream>>>(h, g1, be1, hnormb, NN);

    // 2. fused QKV gemm: Q bf16, K/V fp8
    dim3 gq(768 / 256, (M + 127) / 128);
    mgemm_k<2, false, false><<<gq, blk512, 0, stream>>>(hnormb, Wqkvt, bqkv, Qb, KV8, nullptr, M, 768, 256);

    // 3. fused edge attention -> hnew (bf16)
    attn_k<<<dim3((NN + 3) / 4), blk, 0, stream>>>(csr, degoff, Qb, KV8, hnewb);

    // 4. h_mid = hnew @ Wo + bo + h -> d_out (f32)
    dim3 go(256 / 256, (M + 127) / 128);
    mgemm_k<0, false, true><<<go, blk512, 0, stream>>>(hnewb, Wot, bo, out, nullptr, h, M, 256, 256);

    // 5. LN2 -> bf16
    ln_k<<<dim3((NN + 3) / 4), blk, 0, stream>>>(out, g2, be2, h2nb, NN);

    // 6. FFN
    dim3 g1x(512 / 256, (M + 127) / 128);
    mgemm_k<1, true, false><<<g1x, blk512, 0, stream>>>(h2nb, W1t, b1, ffnmid, nullptr, nullptr, M, 512, 256);
    mgemm_k<0, false, true><<<go, blk512, 0, stream>>>(ffnmid, W2t, b2, out, nullptr, out, M, 256, 512);
}

// Round 8
// 684.191 us; speedup vs baseline: 3.8049x; 1.0255x over previous
//
#include <hip/hip_runtime.h>
#include <hip/hip_bf16.h>

#define NN 100000
#define NE 1600000
// HID=256, HEADS=4, HEAD_DIM=64

typedef __attribute__((ext_vector_type(8))) short bf16x8;
typedef __attribute__((ext_vector_type(4))) float f32x4;
typedef __attribute__((ext_vector_type(2))) float f32x2;
typedef __attribute__((ext_vector_type(2))) unsigned int u32x2;
typedef __attribute__((ext_vector_type(4))) unsigned int u32x4;

// ---------- helpers ----------
__device__ __forceinline__ float bf2f(unsigned short u) {
    union { unsigned int i; float f; } c; c.i = ((unsigned int)u) << 16; return c.f;
}
__device__ __forceinline__ unsigned short f2bf(float f) {
    union { float f; unsigned int i; } c; c.f = f;
    unsigned int lsb = (c.i >> 16) & 1u;
    c.i += 0x7FFFu + lsb;   // round-to-nearest-even
    return (unsigned short)(c.i >> 16);
}
__device__ __forceinline__ u32x4 pack8bf(f32x4 a, f32x4 b) {
    u32x4 p;
    p.x = f2bf(a[0]) | ((unsigned int)f2bf(a[1]) << 16);
    p.y = f2bf(a[2]) | ((unsigned int)f2bf(a[3]) << 16);
    p.z = f2bf(b[0]) | ((unsigned int)f2bf(b[1]) << 16);
    p.w = f2bf(b[2]) | ((unsigned int)f2bf(b[3]) << 16);
    return p;
}
__device__ __forceinline__ void gload_lds16(const void* g, void* l) {
    __builtin_amdgcn_global_load_lds(
        (const __attribute__((address_space(1))) void*)g,
        (__attribute__((address_space(3))) void*)l, 16, 0, 0);
}

// ---------- LayerNorm (LN1): 4 rows/block, 1 wave/row, bf16 out ----------
__global__ __launch_bounds__(256) void ln_k(
    const float* __restrict__ x, const float* __restrict__ g,
    const float* __restrict__ b, unsigned short* __restrict__ y, int nrows)
{
    int w = threadIdx.x >> 6, lane = threadIdx.x & 63;
    int row = blockIdx.x * 4 + w;
    if (row >= nrows) return;
    const float4 xv = *(const float4*)(x + (size_t)row * 256 + lane * 4);
    float s  = xv.x + xv.y + xv.z + xv.w;
    float sq = xv.x*xv.x + xv.y*xv.y + xv.z*xv.z + xv.w*xv.w;
    #pragma unroll
    for (int m = 1; m < 64; m <<= 1) {
        s  += __shfl_xor(s,  m);
        sq += __shfl_xor(sq, m);
    }
    float mu  = s * (1.0f / 256.0f);
    float var = sq * (1.0f / 256.0f) - mu * mu;
    float r = rsqrtf(var + 1e-5f);
    float4 gv = *(const float4*)(g + lane * 4);
    float4 bv = *(const float4*)(b + lane * 4);
    ushort4 o;
    o.x = f2bf((xv.x - mu) * r * gv.x + bv.x);
    o.y = f2bf((xv.y - mu) * r * gv.y + bv.y);
    o.z = f2bf((xv.z - mu) * r * gv.z + bv.z);
    o.w = f2bf((xv.w - mu) * r * gv.w + bv.w);
    *(ushort4*)(y + (size_t)row * 256 + lane * 4) = o;
}

// ---------- weight transpose + f32->bf16: Wt[n][k] = W[k][n] ----------
__global__ __launch_bounds__(256) void wconv_k(
    const float* __restrict__ W, unsigned short* __restrict__ Wt, int K, int N)
{
    __shared__ unsigned short tl[32][33];
    int bk = blockIdx.x * 32, bn = blockIdx.y * 32;
    int lx = threadIdx.x & 31, ly = threadIdx.x >> 5;   // ly 0..7
    #pragma unroll
    for (int r = 0; r < 32; r += 8)
        tl[ly + r][lx] = f2bf(W[(size_t)(bk + ly + r) * N + bn + lx]);
    __syncthreads();
    #pragma unroll
    for (int r = 0; r < 32; r += 8)
        Wt[(size_t)(bn + ly + r) * K + bk + lx] = tl[lx][ly + r];
}

// ---------- concat 3 bias vectors of 256 into one 768 ----------
__global__ void bcat_k(const float* __restrict__ a, const float* __restrict__ b,
                       const float* __restrict__ c, float* __restrict__ o)
{
    int t = threadIdx.x;
    o[t] = a[t]; o[256 + t] = b[t]; o[512 + t] = c[t];
}

// ---------- MFMA bf16 GEMM v3 ----------
// 128x256 tile, BK=32 double-buffered, 512 threads = 8 waves (2Mx4N), wave = 64x64
// OMODE: 0 f32 out | 1 bf16 out | 2 QKV split (Q bf16 / KV fp8)
//        3 Wo+LN2 fused: outv=h2 bf16 (normalized, g/be), out2=hmid bf16 raw, res=h f32
//        4 f32 out with bf16 res
template<int OMODE, bool RELU, bool RES>
__global__ __launch_bounds__(512) void mgemm_k(
    const unsigned short* __restrict__ A, const unsigned short* __restrict__ Wt,
    const float* __restrict__ bias, void* __restrict__ outv, void* __restrict__ out2,
    const void* __restrict__ res, const float* __restrict__ g, const float* __restrict__ be,
    int M, int N, int K)
{
    __shared__ __align__(16) char lds[49152];   // A dbuf 2x8KB @0, B dbuf 2x16KB @16384
    const int t = threadIdx.x;
    const int lane = t & 63;
    const int wid = t >> 6;                 // 0..7
    const int wm = wid >> 2, wn = wid & 3;  // 2 x 4
    const int bm = blockIdx.y * 128, bn = blockIdx.x * 256;

    f32x4 acc[4][4] = {};

    const int ra_s = t >> 2;
    const int sa_s = (t & 3) ^ (ra_s & 3);
    const size_t arow = (size_t)min(bm + ra_s, M - 1) * K + sa_s * 8;
    const int rb0 = t >> 2;
    const int sb0 = (t & 3) ^ (rb0 & 3);
    const int rb1 = (512 + t) >> 2;
    const int sb1 = (t & 3) ^ (rb1 & 3);
    const size_t brow0 = (size_t)(bn + rb0) * K + sb0 * 8;
    const size_t brow1 = (size_t)(bn + rb1) * K + sb1 * 8;

    const int fr = lane & 15, fs = lane >> 4;
    const int rslot = fs ^ (fr & 3);

    const int KS = K >> 5;
    int cur = 0;
    {
        unsigned short* Ab = (unsigned short*)(lds);
        unsigned short* Bb = (unsigned short*)(lds + 16384);
        gload_lds16(A + arow, Ab + t * 8);
        gload_lds16(Wt + brow0, Bb + t * 8);
        gload_lds16(Wt + brow1, Bb + (512 + t) * 8);
    }
    for (int ks = 0; ks < KS; ++ks) {
        __syncthreads();
        if (ks + 1 < KS) {
            int k1 = (ks + 1) << 5;
            unsigned short* Ab = (unsigned short*)(lds + (cur ^ 1) * 8192);
            unsigned short* Bb = (unsigned short*)(lds + 16384 + (cur ^ 1) * 16384);
            gload_lds16(A + arow + k1, Ab + t * 8);
            gload_lds16(Wt + brow0 + k1, Bb + t * 8);
            gload_lds16(Wt + brow1 + k1, Bb + (512 + t) * 8);
        }
        const unsigned short* As = (const unsigned short*)(lds + cur * 8192);
        const unsigned short* Bs = (const unsigned short*)(lds + 16384 + cur * 16384);
        bf16x8 af[4], bf[4];
        #pragma unroll
        for (int fm = 0; fm < 4; ++fm)
            af[fm] = *(const bf16x8*)&As[(wm * 64 + fm * 16 + fr) * 32 + rslot * 8];
        #pragma unroll
        for (int fn = 0; fn < 4; ++fn)
            bf[fn] = *(const bf16x8*)&Bs[(wn * 64 + fn * 16 + fr) * 32 + rslot * 8];
        #pragma unroll
        for (int fm = 0; fm < 4; ++fm)
            #pragma unroll
            for (int fn = 0; fn < 4; ++fn)
                acc[fm][fn] = __builtin_amdgcn_mfma_f32_16x16x32_bf16(
                    af[fm], bf[fn], acc[fm][fn], 0, 0, 0);
        cur ^= 1;
    }
    __syncthreads();   // staging LDS dead; reuse for epilogue

    // epilogue: per-wave LDS bounce [16 rows][68 stride f32] -> wide row-major values
    float* wl = (float*)(lds + wid * 4352);       // 8 waves * 4352B = 34816
    float* stats = (float*)(lds + 34816);         // [128 rows][4 wn][2] f32 = 4KB
    const int rr = lane >> 2;
    const int c4 = (lane & 3) * 16;
    const int qg = lane >> 4;

    #pragma unroll
    for (int fm = 0; fm < 4; ++fm) {
        #pragma unroll
        for (int fn = 0; fn < 4; ++fn)
            #pragma unroll
            for (int i = 0; i < 4; ++i)
                wl[(qg * 4 + i) * 68 + fn * 16 + fr] = acc[fm][fn][i];
        f32x4 v0 = *(const f32x4*)&wl[rr * 68 + c4 + 0];
        f32x4 v1 = *(const f32x4*)&wl[rr * 68 + c4 + 4];
        f32x4 v2 = *(const f32x4*)&wl[rr * 68 + c4 + 8];
        f32x4 v3 = *(const f32x4*)&wl[rr * 68 + c4 + 12];
        const int rowg = bm + wm * 64 + fm * 16 + rr;
        const int colg = bn + wn * 64 + c4;
        if (rowg < M) {
            v0 += *(const f32x4*)&bias[colg + 0];
            v1 += *(const f32x4*)&bias[colg + 4];
            v2 += *(const f32x4*)&bias[colg + 8];
            v3 += *(const f32x4*)&bias[colg + 12];
            if (RES) {
                if (OMODE == 4) {
                    const unsigned short* rp = (const unsigned short*)res + (size_t)rowg * N + colg;
                    u32x4 ra = *(const u32x4*)rp;
                    u32x4 rb = *(const u32x4*)(rp + 8);
                    v0[0] += bf2f(ra.x & 0xffff); v0[1] += bf2f(ra.x >> 16);
                    v0[2] += bf2f(ra.y & 0xffff); v0[3] += bf2f(ra.y >> 16);
                    v1[0] += bf2f(ra.z & 0xffff); v1[1] += bf2f(ra.z >> 16);
                    v1[2] += bf2f(ra.w & 0xffff); v1[3] += bf2f(ra.w >> 16);
                    v2[0] += bf2f(rb.x & 0xffff); v2[1] += bf2f(rb.x >> 16);
                    v2[2] += bf2f(rb.y & 0xffff); v2[3] += bf2f(rb.y >> 16);
                    v3[0] += bf2f(rb.z & 0xffff); v3[1] += bf2f(rb.z >> 16);
                    v3[2] += bf2f(rb.w & 0xffff); v3[3] += bf2f(rb.w >> 16);
                } else {
                    const float* rp = (const float*)res + (size_t)rowg * N + colg;
                    v0 += *(const f32x4*)(rp + 0);
                    v1 += *(const f32x4*)(rp + 4);
                    v2 += *(const f32x4*)(rp + 8);
                    v3 += *(const f32x4*)(rp + 12);
                }
            }
            if (RELU) {
                #pragma unroll
                for (int j = 0; j < 4; ++j) {
                    v0[j] = fmaxf(v0[j], 0.f); v1[j] = fmaxf(v1[j], 0.f);
                    v2[j] = fmaxf(v2[j], 0.f); v3[j] = fmaxf(v3[j], 0.f);
                }
            }
        } else {
            v0 = 0.f; v1 = 0.f; v2 = 0.f; v3 = 0.f;
        }

        if (OMODE == 3) {
            // keep full-precision values in acc for the LN pass
            acc[fm][0] = v0; acc[fm][1] = v1; acc[fm][2] = v2; acc[fm][3] = v3;
        } else if (rowg < M) {
            if (OMODE == 0 || OMODE == 4) {
                float* op = (float*)outv + (size_t)rowg * N + colg;
                *(f32x4*)(op + 0) = v0; *(f32x4*)(op + 4) = v1;
                *(f32x4*)(op + 8) = v2; *(f32x4*)(op + 12) = v3;
            } else if (OMODE == 1) {
                unsigned short* op = (unsigned short*)outv + (size_t)rowg * N + colg;
                *(u32x4*)(op + 0) = pack8bf(v0, v1);
                *(u32x4*)(op + 8) = pack8bf(v2, v3);
            } else {  // OMODE 2
                if (colg < 256) {
                    unsigned short* op = (unsigned short*)outv + (size_t)rowg * 256 + colg;
                    *(u32x4*)(op + 0) = pack8bf(v0, v1);
                    *(u32x4*)(op + 8) = pack8bf(v2, v3);
                } else {
                    u32x4 p8;
                    unsigned int w0, w1, w2, w3;
                    w0 = __builtin_amdgcn_cvt_pk_fp8_f32(v0[0], v0[1], 0, false);
                    w0 = __builtin_amdgcn_cvt_pk_fp8_f32(v0[2], v0[3], w0, true);
                    w1 = __builtin_amdgcn_cvt_pk_fp8_f32(v1[0], v1[1], 0, false);
                    w1 = __builtin_amdgcn_cvt_pk_fp8_f32(v1[2], v1[3], w1, true);
                    w2 = __builtin_amdgcn_cvt_pk_fp8_f32(v2[0], v2[1], 0, false);
                    w2 = __builtin_amdgcn_cvt_pk_fp8_f32(v2[2], v2[3], w2, true);
                    w3 = __builtin_amdgcn_cvt_pk_fp8_f32(v3[0], v3[1], 0, false);
                    w3 = __builtin_amdgcn_cvt_pk_fp8_f32(v3[2], v3[3], w3, true);
                    p8.x = w0; p8.y = w1; p8.z = w2; p8.w = w3;
                    *(u32x4*)((unsigned char*)out2 + (size_t)rowg * 512 + (colg - 256)) = p8;
                }
            }
        }
    }

    if (OMODE == 3) {
        // row stats: per-lane partial over its 16 cols, reduce across 4-lane quad, then 4 wn-waves via LDS
        #pragma unroll
        for (int fm = 0; fm < 4; ++fm) {
            float s = 0.f, q = 0.f;
            #pragma unroll
            for (int j = 0; j < 4; ++j)
                #pragma unroll
                for (int c = 0; c < 4; ++c) {
                    float x = acc[fm][j][c];
                    s += x; q += x * x;
                }
            s += __shfl_xor(s, 1); q += __shfl_xor(q, 1);
            s += __shfl_xor(s, 2); q += __shfl_xor(q, 2);
            if ((lane & 3) == 0) {
                int rowl = wm * 64 + fm * 16 + rr;
                stats[rowl * 8 + wn * 2 + 0] = s;
                stats[rowl * 8 + wn * 2 + 1] = q;
            }
        }
        __syncthreads();
        #pragma unroll
        for (int fm = 0; fm < 4; ++fm) {
            const int rowl = wm * 64 + fm * 16 + rr;
            const int rowg = bm + rowl;
            float s = stats[rowl * 8 + 0] + stats[rowl * 8 + 2] + stats[rowl * 8 + 4] + stats[rowl * 8 + 6];
            float q = stats[rowl * 8 + 1] + stats[rowl * 8 + 3] + stats[rowl * 8 + 5] + stats[rowl * 8 + 7];
            float mu = s * (1.0f / 256.0f);
            float var = q * (1.0f / 256.0f) - mu * mu;
            float rstd = rsqrtf(var + 1e-5f);
            const int colg = bn + wn * 64 + c4;
            if (rowg < M) {
                // hmid raw bf16
                unsigned short* mp = (unsigned short*)out2 + (size_t)rowg * 256 + colg;
                *(u32x4*)(mp + 0) = pack8bf(acc[fm][0], acc[fm][1]);
                *(u32x4*)(mp + 8) = pack8bf(acc[fm][2], acc[fm][3]);
                // h2 normalized bf16
                f32x4 nv[4];
                #pragma unroll
                for (int j = 0; j < 4; ++j) {
                    f32x4 gv = *(const f32x4*)&g[colg + j * 4];
                    f32x4 bv = *(const f32x4*)&be[colg + j * 4];
                    #pragma unroll
                    for (int c = 0; c < 4; ++c)
                        nv[j][c] = (acc[fm][j][c] - mu) * rstd * gv[c] + bv[c];
                }
                unsigned short* op = (unsigned short*)outv + (size_t)rowg * 256 + colg;
                *(u32x4*)(op + 0) = pack8bf(nv[0], nv[1]);
                *(u32x4*)(op + 8) = pack8bf(nv[2], nv[3]);
            }
        }
    }
}

// ---------- degree count ----------
__global__ void degcnt_k(const int* __restrict__ dst, int* __restrict__ deg, int E)
{
    int e = blockIdx.x * blockDim.x + threadIdx.x;
    if (e < E) atomicAdd(deg + dst[e], 1);
}

// ---------- single-block exclusive scan (in place), total at a[n] ----------
__global__ __launch_bounds__(1024) void scan_k(int* __restrict__ a, int n)
{
    __shared__ int wsum[16];
    __shared__ int carry;
    __shared__ int tot;
    int t = threadIdx.x, lane = t & 63, w = t >> 6;
    if (t == 0) carry = 0;
    __syncthreads();
    for (int base = 0; base < n; base += 1024) {
        int i = base + t;
        int v = (i < n) ? a[i] : 0;
        int s = v;
        #pragma unroll
        for (int d2 = 1; d2 < 64; d2 <<= 1) {
            int u = __shfl_up(s, d2);
            if (lane >= d2) s += u;
        }
        if (lane == 63) wsum[w] = s;
        __syncthreads();
        if (t == 0) {
            int run = 0;
            #pragma unroll
            for (int j = 0; j < 16; ++j) { int x = wsum[j]; wsum[j] = run; run += x; }
            tot = run;
        }
        __syncthreads();
        int excl = carry + wsum[w] + (s - v);
        if (i < n) a[i] = excl;
        __syncthreads();
        if (t == 0) carry += tot;
        __syncthreads();
    }
    if (threadIdx.x == 0) a[n] = carry;
}

// ---------- CSR scatter: csr[pos] = src ----------
__global__ void scatter_k(
    const int* __restrict__ dst, const int* __restrict__ srcarr,
    const int* __restrict__ off, int* __restrict__ cursor,
    int* __restrict__ csr, int E)
{
    int e = blockIdx.x * blockDim.x + threadIdx.x;
    if (e >= E) return;
    int d = dst[e];
    int pos = off[d] + atomicAdd(cursor + d, 1);
    csr[pos] = srcarr[e];
}

// ---------- fused edge attention: 1 wave / node, flat softmax, fp8 K/V ----------
__global__ __launch_bounds__(256) void attn_k(
    const int* __restrict__ csr, const int* __restrict__ off,
    const unsigned short* __restrict__ Q, const unsigned char* __restrict__ KV8,
    unsigned short* __restrict__ hnew)
{
    int w = threadIdx.x >> 6, lane = threadIdx.x & 63;
    int n = blockIdx.x * 4 + w;
    if (n >= NN) return;
    int e0 = off[n], e1 = off[n + 1];

    u32x2 qr = __builtin_nontemporal_load((const u32x2*)(Q + (size_t)n * 256 + lane * 4));
    const float q0 = bf2f((unsigned short)(qr.x & 0xffff)) * 0.125f;
    const float q1 = bf2f((unsigned short)(qr.x >> 16))    * 0.125f;
    const float q2 = bf2f((unsigned short)(qr.y & 0xffff)) * 0.125f;
    const float q3 = bf2f((unsigned short)(qr.y >> 16))    * 0.125f;

    float s = 0.f;
    float a0 = 0.f, a1 = 0.f, a2 = 0.f, a3 = 0.f;

    int i = e0;
    for (; i + 7 < e1; i += 8) {
        int ns[8];
        #pragma unroll
        for (int j = 0; j < 8; ++j) ns[j] = csr[i + j];
        unsigned int kd[8], vd[8];
        #pragma unroll
        for (int j = 0; j < 8; ++j) {
            const unsigned char* r = KV8 + (size_t)ns[j] * 512 + lane * 4;
            kd[j] = *(const unsigned int*)r;
            vd[j] = *(const unsigned int*)(r + 256);
        }
        float l[8];
        #pragma unroll
        for (int j = 0; j < 8; ++j) {
            f32x2 ka = __builtin_amdgcn_cvt_pk_f32_fp8(kd[j], false);
            f32x2 kb = __builtin_amdgcn_cvt_pk_f32_fp8(kd[j], true);
            l[j] = q0 * ka.x + q1 * ka.y + q2 * kb.x + q3 * kb.y;
        }
        #pragma unroll
        for (int m2 = 1; m2 < 16; m2 <<= 1) {
            #pragma unroll
            for (int j = 0; j < 8; ++j) l[j] += __shfl_xor(l[j], m2);
        }
        #pragma unroll
        for (int j = 0; j < 8; ++j) {
            float p = __expf(l[j]);
            f32x2 va = __builtin_amdgcn_cvt_pk_f32_fp8(vd[j], false);
            f32x2 vb = __builtin_amdgcn_cvt_pk_f32_fp8(vd[j], true);
            s  += p;
            a0 += p * va.x; a1 += p * va.y;
            a2 += p * vb.x; a3 += p * vb.y;
        }
    }
    for (; i + 3 < e1; i += 4) {
        int ns[4];
        #pragma unroll
        for (int j = 0; j < 4; ++j) ns[j] = csr[i + j];
        unsigned int kd[4], vd[4];
        #pragma unroll
        for (int j = 0; j < 4; ++j) {
            const unsigned char* r = KV8 + (size_t)ns[j] * 512 + lane * 4;
            kd[j] = *(const unsigned int*)r;
            vd[j] = *(const unsigned int*)(r + 256);
        }
        float l[4];
        #pragma unroll
        for (int j = 0; j < 4; ++j) {
            f32x2 ka = __builtin_amdgcn_cvt_pk_f32_fp8(kd[j], false);
            f32x2 kb = __builtin_amdgcn_cvt_pk_f32_fp8(kd[j], true);
            l[j] = q0 * ka.x + q1 * ka.y + q2 * kb.x + q3 * kb.y;
        }
        #pragma unroll
        for (int m2 = 1; m2 < 16; m2 <<= 1) {
            #pragma unroll
            for (int j = 0; j < 4; ++j) l[j] += __shfl_xor(l[j], m2);
        }
        #pragma unroll
        for (int j = 0; j < 4; ++j) {
            float p = __expf(l[j]);
            f32x2 va = __builtin_amdgcn_cvt_pk_f32_fp8(vd[j], false);
            f32x2 vb = __builtin_amdgcn_cvt_pk_f32_fp8(vd[j], true);
            s  += p;
            a0 += p * va.x; a1 += p * va.y;
            a2 += p * vb.x; a3 += p * vb.y;
        }
    }
    for (; i < e1; ++i) {
        int n0 = csr[i];
        const unsigned char* r = KV8 + (size_t)n0 * 512 + lane * 4;
        unsigned int kd = *(const unsigned int*)r;
        unsigned int vd = *(const unsigned int*)(r + 256);
        f32x2 ka = __builtin_amdgcn_cvt_pk_f32_fp8(kd, false);
        f32x2 kb = __builtin_amdgcn_cvt_pk_f32_fp8(kd, true);
        float l0 = q0 * ka.x + q1 * ka.y + q2 * kb.x + q3 * kb.y;
        #pragma unroll
        for (int m2 = 1; m2 < 16; m2 <<= 1) l0 += __shfl_xor(l0, m2);
        float p = __expf(l0);
        f32x2 va = __builtin_amdgcn_cvt_pk_f32_fp8(vd, false);
        f32x2 vb = __builtin_amdgcn_cvt_pk_f32_fp8(vd, true);
        s  += p;
        a0 += p * va.x; a1 += p * va.y;
        a2 += p * vb.x; a3 += p * vb.y;
    }
    float inv = (e1 > e0) ? 1.0f / s : 0.f;
    u32x2 ov;
    ov.x = ((unsigned int)f2bf(a1 * inv) << 16) | f2bf(a0 * inv);
    ov.y = ((unsigned int)f2bf(a3 * inv) << 16) | f2bf(a2 * inv);
    __builtin_nontemporal_store(ov, (u32x2*)(hnew + (size_t)n * 256 + lane * 4));
}

// ---------- host ----------
extern "C" void kernel_launch(void* const* d_in, const int* in_sizes, int n_in,
                              void* d_out, int out_size, void* d_ws, size_t ws_size,
                              hipStream_t stream)
{
    if (n_in < 19) return;
    const float* h   = (const float*)d_in[0];
    const int*   src = (const int*)d_in[1];
    const int*   dst = (const int*)d_in[2];
    const float* Wq  = (const float*)d_in[3];
    const float* bq  = (const float*)d_in[4];
    const float* Wk  = (const float*)d_in[5];
    const float* bk  = (const float*)d_in[6];
    const float* Wv  = (const float*)d_in[7];
    const float* bv  = (const float*)d_in[8];
    const float* Wo  = (const float*)d_in[9];
    const float* bo  = (const float*)d_in[10];
    const float* W1  = (const float*)d_in[11];
    const float* b1  = (const float*)d_in[12];
    const float* W2  = (const float*)d_in[13];
    const float* b2  = (const float*)d_in[14];
    const float* g1  = (const float*)d_in[15];
    const float* be1 = (const float*)d_in[16];
    const float* g2  = (const float*)d_in[17];
    const float* be2 = (const float*)d_in[18];
    float* out = (float*)d_out;

    char* w = (char*)d_ws;
    // layout (bytes):
    unsigned short* hnormb = (unsigned short*)(w + 0);            //  51,200,000 (hnorm -> hnew -> h2, in place)
    unsigned short* Qb     = (unsigned short*)(w + 51200000);     //  51,200,000 (Q -> hmid)
    unsigned char*  KV8    = (unsigned char*)(w + 102400000);     //  51,200,000 (fp8 K|V, dead after attn)
    int*            degoff = (int*)(w + 153600000);               //     400,384 (dead after attn)
    int*            cursor = (int*)(w + 154000384);               //     400,384
    int*            csr    = (int*)(w + 154400768);               //   6,400,000 -> 160,800,768 (dead after attn)
    unsigned short* Wqkvt  = (unsigned short*)(w + 204800000);    //     393,216 (768x256)
    unsigned short* Wot    = (unsigned short*)(w + 205193216);    //     131,072
    unsigned short* W1t    = (unsigned short*)(w + 205324288);    //     262,144
    unsigned short* W2t    = (unsigned short*)(w + 205586432);    //     262,144
    float*          bqkv   = (float*)(w + 205848576);             //       3,072 -> 205,851,648
    // aliases (temporally disjoint):
    unsigned short* hnewb  = hnormb;                          // hnorm dead after QKV gemm
    unsigned short* h2nb   = hnormb;                          // hnew dead after Wo gemm (in-place, block-local)
    unsigned short* hmidb  = Qb;                              // Q dead after attn
    unsigned short* ffnmid = (unsigned short*)(w + 102400000);// KV8+csr dead after attn (102.4MB span)

    hipMemsetAsync(degoff, 0, 400384, stream);
    hipMemsetAsync(cursor, 0, 400384, stream);

    const int M = NN;
    dim3 blk(256);
    dim3 blk512(512);

    // weight conversion (transpose to [N][K] bf16); QKV concatenated row-wise
    wconv_k<<<dim3(8, 8),  blk, 0, stream>>>(Wq, Wqkvt,             256, 256);
    wconv_k<<<dim3(8, 8),  blk, 0, stream>>>(Wk, Wqkvt + 256 * 256, 256, 256);
    wconv_k<<<dim3(8, 8),  blk, 0, stream>>>(Wv, Wqkvt + 512 * 256, 256, 256);
    wconv_k<<<dim3(8, 8),  blk, 0, stream>>>(Wo, Wot, 256, 256);
    wconv_k<<<dim3(8, 16), blk, 0, stream>>>(W1, W1t, 256, 512);
    wconv_k<<<dim3(16, 8), blk, 0, stream>>>(W2, W2t, 512, 256);
    bcat_k<<<dim3(1), blk, 0, stream>>>(bq, bk, bv, bqkv);

    // CSR build
    degcnt_k<<<dim3((NE + 255) / 256), blk, 0, stream>>>(dst, degoff, NE);
    scan_k<<<dim3(1), dim3(1024), 0, stream>>>(degoff, NN);
    scatter_k<<<dim3((NE + 255) / 256), blk, 0, stream>>>(dst, src, degoff, cursor, csr, NE);

    // 1. LN1 -> bf16
    ln_k<<<dim3((NN + 3) / 4), blk, 0, stream>>>(h, g1, be1, hnormb, NN);

    // 2. fused QKV gemm: Q bf16, K/V fp8
    dim3 gq(768 / 256, (M + 127) / 128);
    mgemm_k<2, false, false><<<gq, blk512, 0, stream>>>(hnormb, Wqkvt, bqkv, Qb, KV8, nullptr, nullptr, nullptr, M, 768, 256);

    // 3. fused edge attention -> hnew (bf16)
    attn_k<<<dim3((NN + 3) / 4), blk, 0, stream>>>(csr, degoff, Qb, KV8, hnewb);

    // 4. Wo gemm + residual + fused LN2 -> h2 (bf16, normalized) + hmid (bf16 raw)
    dim3 go(1, (M + 127) / 128);
    mgemm_k<3, false, true><<<go, blk512, 0, stream>>>(hnewb, Wot, bo, h2nb, hmidb, h, g2, be2, M, 256, 256);

    // 5. FFN
    dim3 g1x(512 / 256, (M + 127) / 128);
    mgemm_k<1, true, false><<<g1x, blk512, 0, stream>>>(h2nb, W1t, b1, ffnmid, nullptr, nullptr, nullptr, nullptr, M, 512, 256);
    mgemm_k<4, false, true><<<go, blk512, 0, stream>>>(ffnmid, W2t, b2, out, nullptr, hmidb, nullptr, nullptr, M, 256, 512);
}